// Round 11
// baseline (934.085 us; speedup 1.0000x reference)
//
#include <hip/hip_runtime.h>
#include <hip/hip_bf16.h>

typedef float f32x4 __attribute__((ext_vector_type(4)));
typedef __bf16 bf16x8 __attribute__((ext_vector_type(8)));

#define DEV __device__ __forceinline__

constexpr int B_ = 8, S_ = 512, D_ = 512, H_ = 8, L_ = 4, DFF_ = 2048, NI_ = 20000, AD_ = 128, DK_ = 64;
constexpr int N_ = B_ * S_;            // 4096 tokens
constexpr int NOUT_PAD = 20224;        // 79 * 256 (256-wide logits tiles)

DEV void gload_lds16(const void* g, void* l) {
  __builtin_amdgcn_global_load_lds((const __attribute__((address_space(1))) unsigned int*)g,
                                   (__attribute__((address_space(3))) unsigned int*)l, 16, 0, 0);
}

// m204 bijective XCD-chunk swizzle
DEV int xcd_swizzle(int bid, int nwg) {
  int q = nwg >> 3, r = nwg & 7;
  int x = bid & 7, idx = bid >> 3;
  int base = (x < r) ? x * (q + 1) : r * (q + 1) + (x - r) * q;
  return base + idx;
}

// ---------------------------------------------------------------------------
// Big-N streaming GEMM: 256xBN tile (BN in {128,256}), BK=32, 8 waves (4Mx2N),
// 512 threads, 2-phase. BK=32 swizzle ch ^= (row>>1)&3 (2-way = free).
// Plain cached loads (NT loads defeat inter-block B reuse - round-9 lesson).
// NT f32 C-stores. BN=256: 64KB LDS -> 2 blocks/CU, staging traffic halved
// vs BN=128 (A 643->323 MB, B panels 157->79).
// ---------------------------------------------------------------------------
template<int BN>
__global__ __launch_bounds__(512)
void gemm_big(const __hip_bfloat16* __restrict__ A, int lda,
              const __hip_bfloat16* __restrict__ Bm, int ldb,
              float* __restrict__ C, int ldc,
              const float* __restrict__ bias, int K, int Ncols)
{
  constexpr int NJ = BN / 32;                    // per-wave N fragments (BN/2/16)
  __shared__ __align__(16) unsigned short smA[2][256 * 32];
  __shared__ __align__(16) unsigned short smB[2][BN * 32];

  const int nwg = gridDim.x * gridDim.y;
  const int bid = blockIdx.y * gridDim.x + blockIdx.x;
  const int wgid = xcd_swizzle(bid, nwg);
  const int m0 = (wgid % gridDim.x) * 256, n0 = (wgid / gridDim.x) * BN;

  const int tid = threadIdx.x, wv = tid >> 6, lane = tid & 63;
  const int l15 = lane & 15, l4 = lane >> 4;
  const int wm = (wv >> 1) * 64, wn = (wv & 1) * (BN / 2);

  auto stage = [&](int buf, int k0) {
#pragma unroll
    for (int it = 0; it < 2; ++it) {               // A: 256 rows x 4 chunks
      int idx = it * 512 + tid, row = idx >> 2, c = idx & 3;
      int sc = c ^ ((row >> 1) & 3);
      gload_lds16((const void*)(A + (size_t)(m0 + row) * lda + k0 + sc * 8),
                  (void*)&smA[buf][(size_t)(it * 512 + wv * 64) * 8]);
    }
#pragma unroll
    for (int it = 0; it < BN / 128; ++it) {        // B: BN rows x 4 chunks
      int idx = it * 512 + tid, row = idx >> 2, c = idx & 3;
      int sc = c ^ ((row >> 1) & 3);
      gload_lds16((const void*)(Bm + (size_t)(n0 + row) * ldb + k0 + sc * 8),
                  (void*)&smB[buf][(size_t)(it * 512 + wv * 64) * 8]);
    }
  };

  f32x4 acc[4][NJ];
#pragma unroll
  for (int i = 0; i < 4; ++i)
#pragma unroll
    for (int j = 0; j < NJ; ++j) acc[i][j] = f32x4{0.f, 0.f, 0.f, 0.f};

  const int nk = K / 32;
  stage(0, 0);
  __syncthreads();

  int cur = 0;
  for (int t = 0; t < nk; ++t) {
    if (t + 1 < nk) stage(cur ^ 1, (t + 1) * 32);  // prefetch issue (async)

    bf16x8 af[4], bfr[NJ];
#pragma unroll
    for (int i = 0; i < 4; ++i) {
      int row = wm + i * 16 + l15;
      int ch = l4 ^ ((row >> 1) & 3);
      af[i] = *reinterpret_cast<const bf16x8*>(&smA[cur][row * 32 + ch * 8]);
    }
#pragma unroll
    for (int j = 0; j < NJ; ++j) {
      int row = wn + j * 16 + l15;
      int ch = l4 ^ ((row >> 1) & 3);
      bfr[j] = *reinterpret_cast<const bf16x8*>(&smB[cur][row * 32 + ch * 8]);
    }
    __builtin_amdgcn_s_setprio(1);
#pragma unroll
    for (int i = 0; i < 4; ++i)
#pragma unroll
      for (int j = 0; j < NJ; ++j)
        acc[i][j] = __builtin_amdgcn_mfma_f32_16x16x32_bf16(af[i], bfr[j], acc[i][j], 0, 0, 0);
    __builtin_amdgcn_s_setprio(0);
    __syncthreads();
    cur ^= 1;
  }

  // epilogue: C/D layout col = lane&15, row = (lane>>4)*4 + r
#pragma unroll
  for (int i = 0; i < 4; ++i) {
#pragma unroll
    for (int j = 0; j < NJ; ++j) {
#pragma unroll
      for (int r = 0; r < 4; ++r) {
        int row = m0 + wm + i * 16 + l4 * 4 + r;
        int col = n0 + wn + j * 16 + l15;
        if (col < Ncols) {
          float v = acc[i][j][r] + bias[col];
          __builtin_nontemporal_store(v, &C[(size_t)row * ldc + col]);
        }
      }
    }
  }
}

// ---------------------------------------------------------------------------
// 2-phase bf16 GEMM, BK=64, T2 XOR-swizzled LDS (verified round 8).
// EPI: 0=f32 store (+NT), 1=bf16 store, 2=Wf+PE (write xf f32 + xb bf16),
//      3=QKV wide (q,k rows; v transposed into vt), 4=gate (sigmoid*xf->bf16),
//      5=f32 store + residual add from p2
// ---------------------------------------------------------------------------
template<int BM, int BN, int EPI, int ACT, int NT>
__global__ __launch_bounds__(256)
void gemm2(const __hip_bfloat16* __restrict__ A, int lda,
           const __hip_bfloat16* __restrict__ Bm, int ldb,
           void* __restrict__ Cv, int ldc,
           const float* __restrict__ bias,
           const void* __restrict__ p1, const void* __restrict__ p2,
           const void* __restrict__ p3,
           int K, int Ncols)
{
  constexpr int BK = 64;
  constexpr int MI = BM / 32, NJ = BN / 32;
  constexpr int LA = BM * BK / 2048, LB = BN * BK / 2048;
  __shared__ __align__(16) unsigned short smA[2][BM * BK];
  __shared__ __align__(16) unsigned short smB[2][BN * BK];

  const int nwg = gridDim.x * gridDim.y;
  const int bid = blockIdx.y * gridDim.x + blockIdx.x;
  const int wgid = xcd_swizzle(bid, nwg);
  const int m0 = (wgid % gridDim.x) * BM, n0 = (wgid / gridDim.x) * BN;

  const int tid = threadIdx.x, wv = tid >> 6, lane = tid & 63;
  const int l15 = lane & 15, l4 = lane >> 4;
  const int wm = (wv >> 1) * (BM / 2), wn = (wv & 1) * (BN / 2);

  auto stage = [&](int buf, int k0) {
#pragma unroll
    for (int it = 0; it < LA; ++it) {
      int idx = it * 256 + tid, row = idx >> 3, c = idx & 7;
      int sc = c ^ (row & 7);
      gload_lds16((const void*)(A + (size_t)(m0 + row) * lda + k0 + sc * 8),
                  (void*)&smA[buf][(size_t)(it * 256 + wv * 64) * 8]);
    }
#pragma unroll
    for (int it = 0; it < LB; ++it) {
      int idx = it * 256 + tid, row = idx >> 3, c = idx & 7;
      int sc = c ^ (row & 7);
      gload_lds16((const void*)(Bm + (size_t)(n0 + row) * ldb + k0 + sc * 8),
                  (void*)&smB[buf][(size_t)(it * 256 + wv * 64) * 8]);
    }
  };

  f32x4 acc[MI][NJ];
#pragma unroll
  for (int i = 0; i < MI; ++i)
#pragma unroll
    for (int j = 0; j < NJ; ++j) acc[i][j] = f32x4{0.f, 0.f, 0.f, 0.f};

  const int nk = K / BK;
  stage(0, 0);
  __syncthreads();

  int cur = 0;
  for (int t = 0; t < nk; ++t) {
    if (t + 1 < nk) stage(cur ^ 1, (t + 1) * BK);

    bf16x8 af[MI][2], bfr[NJ][2];
#pragma unroll
    for (int i = 0; i < MI; ++i)
#pragma unroll
      for (int kk = 0; kk < 2; ++kk) {
        int row = wm + i * 16 + l15;
        int ch = (kk * 4 + l4) ^ (row & 7);
        af[i][kk] = *reinterpret_cast<const bf16x8*>(&smA[cur][row * BK + ch * 8]);
      }
#pragma unroll
    for (int j = 0; j < NJ; ++j)
#pragma unroll
      for (int kk = 0; kk < 2; ++kk) {
        int row = wn + j * 16 + l15;
        int ch = (kk * 4 + l4) ^ (row & 7);
        bfr[j][kk] = *reinterpret_cast<const bf16x8*>(&smB[cur][row * BK + ch * 8]);
      }
    __builtin_amdgcn_s_setprio(1);
#pragma unroll
    for (int kk = 0; kk < 2; ++kk)
#pragma unroll
      for (int i = 0; i < MI; ++i)
#pragma unroll
        for (int j = 0; j < NJ; ++j)
          acc[i][j] = __builtin_amdgcn_mfma_f32_16x16x32_bf16(af[i][kk], bfr[j][kk], acc[i][j], 0, 0, 0);
    __builtin_amdgcn_s_setprio(0);
    __syncthreads();
    cur ^= 1;
  }

#pragma unroll
  for (int i = 0; i < MI; ++i) {
#pragma unroll
    for (int j = 0; j < NJ; ++j) {
#pragma unroll
      for (int r = 0; r < 4; ++r) {
        int row = m0 + wm + i * 16 + l4 * 4 + r;
        int col = n0 + wn + j * 16 + l15;
        if (col < Ncols) {
          float v = acc[i][j][r];
          if (bias) v += bias[col];
          if (ACT == 1) v = v > 0.f ? v : 0.f;
          if constexpr (EPI == 0) {
            float* dst = &((float*)Cv)[(size_t)row * ldc + col];
            if constexpr (NT) __builtin_nontemporal_store(v, dst);
            else *dst = v;
          } else if constexpr (EPI == 1) {
            ((__hip_bfloat16*)Cv)[(size_t)row * ldc + col] = __float2bfloat16(v);
          } else if constexpr (EPI == 2) {
            v += ((const float*)p2)[(size_t)(row & 511) * 512 + col];
            ((float*)Cv)[(size_t)row * ldc + col] = v;
            ((__hip_bfloat16*)p1)[(size_t)row * ldc + col] = __float2bfloat16(v);
          } else if constexpr (EPI == 3) {
            if (col < 1024) {
              ((__hip_bfloat16*)Cv)[(size_t)(col >> 9) * N_ * 512 + (size_t)row * 512 + (col & 511)] =
                  __float2bfloat16(v);
            } else {
              int hd = col - 1024, b = row >> 9, s = row & 511;
              ((__hip_bfloat16*)p1)[((size_t)(b * 8 + (hd >> 6)) * 64 + (hd & 63)) * 512 + s] =
                  __float2bfloat16(v);
            }
          } else if constexpr (EPI == 4) {
            float zz = v + ((const float*)p2)[row] * ((const float*)p3)[col];
            float sg = 1.f / (1.f + __expf(-zz));
            float xn = ((const float*)p1)[(size_t)row * 512 + col];
            ((__hip_bfloat16*)Cv)[(size_t)row * 512 + col] = __float2bfloat16(xn * sg);
          } else if constexpr (EPI == 5) {
            v += ((const float*)p2)[(size_t)row * 512 + col];   // residual
            ((float*)Cv)[(size_t)row * ldc + col] = v;
          }
        }
      }
    }
  }
}

// ---------------------------------------------------------------------------
// Fused flash attention (verified round 5).
// ---------------------------------------------------------------------------
__global__ __launch_bounds__(256)
void k_flash(const __hip_bfloat16* __restrict__ q, const __hip_bfloat16* __restrict__ k,
             const __hip_bfloat16* __restrict__ vt, const float* __restrict__ mask,
             __hip_bfloat16* __restrict__ ctx)
{
  __shared__ __align__(16) unsigned short Ql[64 * 64];
  __shared__ __align__(16) unsigned short Kl[2][64 * 64];
  __shared__ __align__(16) unsigned short Vl[2][64 * 64];
  __shared__ __align__(16) unsigned short Pl[4][16 * 64];

  const int qt = blockIdx.x, bh = blockIdx.y;
  const int b = bh >> 3, h = bh & 7;
  const int tid = threadIdx.x, wv = tid >> 6, lane = tid & 63;
  const int l15 = lane & 15, l4 = lane >> 4;
  const int q0 = qt * 64;

  const __hip_bfloat16* Qg = q + ((size_t)(b * 512 + q0) * 512) + h * 64;
  const __hip_bfloat16* Kg = k + ((size_t)(b * 512) * 512) + h * 64;
  const __hip_bfloat16* Vg = vt + ((size_t)bh * 64) * 512;
  const float* mk = mask + b * 512;

  auto stageQ = [&]() {
#pragma unroll
    for (int it = 0; it < 2; ++it) {
      int idx = it * 256 + wv * 64 + lane;
      int row = idx >> 3, c = idx & 7;
      gload_lds16((const void*)(Qg + (size_t)row * 512 + (c ^ (row & 7)) * 8),
                  (void*)&Ql[(it * 256 + wv * 64) * 8]);
    }
  };
  auto stageKV = [&](int buf, int kv0) {
#pragma unroll
    for (int it = 0; it < 2; ++it) {
      int idx = it * 256 + wv * 64 + lane;
      int row = idx >> 3, c = idx & 7;
      gload_lds16((const void*)(Kg + (size_t)(kv0 + row) * 512 + (c ^ (row & 7)) * 8),
                  (void*)&Kl[buf][(it * 256 + wv * 64) * 8]);
    }
#pragma unroll
    for (int it = 0; it < 2; ++it) {
      int idx = it * 256 + wv * 64 + lane;
      int row = idx >> 3, c = idx & 7;
      gload_lds16((const void*)(Vg + (size_t)row * 512 + kv0 + (c ^ (row & 7)) * 8),
                  (void*)&Vl[buf][(it * 256 + wv * 64) * 8]);
    }
  };

  stageQ();
  stageKV(0, 0);
  __syncthreads();

  bf16x8 aq[2];
#pragma unroll
  for (int kk = 0; kk < 2; ++kk) {
    int row = wv * 16 + l15;
    aq[kk] = *reinterpret_cast<const bf16x8*>(
        &Ql[row * 64 + (((kk * 4 + l4) ^ (row & 7)) * 8)]);
  }

  f32x4 accO[4];
  float mrun[4], lrun[4];
#pragma unroll
  for (int j = 0; j < 4; ++j) accO[j] = f32x4{0.f, 0.f, 0.f, 0.f};
#pragma unroll
  for (int r = 0; r < 4; ++r) { mrun[r] = -3e38f; lrun[r] = 0.f; }

  int cur = 0;
  for (int t = 0; t < 8; ++t) {
    if (t + 1 < 8) stageKV(cur ^ 1, (t + 1) * 64);
    const int kv0 = t * 64;

    f32x4 s[4];
#pragma unroll
    for (int j = 0; j < 4; ++j) s[j] = f32x4{0.f, 0.f, 0.f, 0.f};
#pragma unroll
    for (int kk = 0; kk < 2; ++kk) {
#pragma unroll
      for (int j = 0; j < 4; ++j) {
        int row = j * 16 + l15;
        bf16x8 bk = *reinterpret_cast<const bf16x8*>(
            &Kl[cur][row * 64 + (((kk * 4 + l4) ^ (row & 7)) * 8)]);
        s[j] = __builtin_amdgcn_mfma_f32_16x16x32_bf16(aq[kk], bk, s[j], 0, 0, 0);
      }
    }

#pragma unroll
    for (int j = 0; j < 4; ++j) {
      float mval = mk[kv0 + j * 16 + l15];
#pragma unroll
      for (int r = 0; r < 4; ++r)
        s[j][r] = (mval == 0.f) ? -1e30f : s[j][r];
    }

    float alpha[4];
#pragma unroll
    for (int r = 0; r < 4; ++r) {
      float v = fmaxf(fmaxf(s[0][r], s[1][r]), fmaxf(s[2][r], s[3][r]));
      v = fmaxf(v, __shfl_xor(v, 1));
      v = fmaxf(v, __shfl_xor(v, 2));
      v = fmaxf(v, __shfl_xor(v, 4));
      v = fmaxf(v, __shfl_xor(v, 8));
      float mn = fmaxf(mrun[r], v);
      alpha[r] = __expf(mrun[r] - mn);
      mrun[r] = mn;
    }
    float rs[4] = {0.f, 0.f, 0.f, 0.f};
#pragma unroll
    for (int j = 0; j < 4; ++j)
#pragma unroll
      for (int r = 0; r < 4; ++r) {
        float p = __expf(s[j][r] - mrun[r]);
        s[j][r] = p;
        rs[r] += p;
      }
#pragma unroll
    for (int r = 0; r < 4; ++r) {
      float v = rs[r];
      v += __shfl_xor(v, 1); v += __shfl_xor(v, 2);
      v += __shfl_xor(v, 4); v += __shfl_xor(v, 8);
      lrun[r] = lrun[r] * alpha[r] + v;
#pragma unroll
      for (int j = 0; j < 4; ++j) accO[j][r] *= alpha[r];
    }

#pragma unroll
    for (int j = 0; j < 4; ++j)
#pragma unroll
      for (int r = 0; r < 4; ++r) {
        int qrow = l4 * 4 + r, key = j * 16 + l15;
        __hip_bfloat16 hb = __float2bfloat16(s[j][r]);
        Pl[wv][qrow * 64 + (((key >> 3) ^ (qrow & 7)) * 8) + (key & 7)] =
            *reinterpret_cast<unsigned short*>(&hb);
      }

#pragma unroll
    for (int kc = 0; kc < 2; ++kc) {
      bf16x8 ap = *reinterpret_cast<const bf16x8*>(
          &Pl[wv][l15 * 64 + (((kc * 4 + l4) ^ (l15 & 7)) * 8)]);
#pragma unroll
      for (int j = 0; j < 4; ++j) {
        int row = j * 16 + l15;
        bf16x8 bv2 = *reinterpret_cast<const bf16x8*>(
            &Vl[cur][row * 64 + (((kc * 4 + l4) ^ (row & 7)) * 8)]);
        accO[j] = __builtin_amdgcn_mfma_f32_16x16x32_bf16(ap, bv2, accO[j], 0, 0, 0);
      }
    }
    __syncthreads();
    cur ^= 1;
  }

#pragma unroll
  for (int r = 0; r < 4; ++r) {
    float inv = lrun[r] > 0.f ? 1.f / lrun[r] : 0.f;
#pragma unroll
    for (int j = 0; j < 4; ++j) {
      int row = q0 + wv * 16 + l4 * 4 + r;
      int col = h * 64 + j * 16 + l15;
      ctx[(size_t)(b * 512 + row) * 512 + col] = __float2bfloat16(accO[j][r] * inv);
    }
  }
}

// ---------------------------------------------------------------------------
// ALL weight transposes + bias pack in ONE launch. 23400 blocks x 256 thr.
// ---------------------------------------------------------------------------
__global__ __launch_bounds__(256)
void k_trans_all(const float* __restrict__ Wa1, const float* __restrict__ Wa2,
                 const float* __restrict__ Wf, const float* __restrict__ Wq,
                 const float* __restrict__ Wk, const float* __restrict__ Wv,
                 const float* __restrict__ Wo, const float* __restrict__ Wff1,
                 const float* __restrict__ Wff2, const float* __restrict__ Wg,
                 const float* __restrict__ Wout,
                 const float* __restrict__ bq, const float* __restrict__ bk,
                 const float* __restrict__ bv,
                 __hip_bfloat16* Wa1T, __hip_bfloat16* Wa2T, __hip_bfloat16* WfT,
                 __hip_bfloat16* WqkvT, __hip_bfloat16* WoT, __hip_bfloat16* Wff1T,
                 __hip_bfloat16* Wff2T, __hip_bfloat16* WgT, __hip_bfloat16* WoutT,
                 float* bqkv)
{
  __shared__ float tile[32][33];
  const int bid = blockIdx.x, tid = threadIdx.x;
  const int tx = tid & 31, ty = tid >> 5;

  auto tr = [&](const float* ip, __hip_bfloat16* op, int K, int N, int NTX,
                int t, float scale) {
    int bx = t % NTX, by = t / NTX;
    int n0 = bx * 32, k0 = by * 32;
#pragma unroll
    for (int r = 0; r < 4; ++r) {
      int k = k0 + ty + r * 8, n = n0 + tx;
      if (k < K && n < N) tile[ty + r * 8][tx] = ip[(size_t)k * N + n];
    }
    __syncthreads();
#pragma unroll
    for (int r = 0; r < 4; ++r) {
      int n = n0 + ty + r * 8, k = k0 + tx;
      if (n < N && k < K) op[(size_t)n * K + k] = __float2bfloat16(tile[tx][ty + r * 8] * scale);
    }
  };

  constexpr int DD = 512 * 512, FD = 512 * 2048;
  if (bid < 64)        tr(Wa1, Wa1T, 128, 512, 16, bid, 1.f);
  else if (bid < 320)  tr(Wa2, Wa2T, 512, 512, 16, bid - 64, 1.f);
  else if (bid < 832)  tr(Wf, WfT, 1024, 512, 16, bid - 320, 1.f);
  else if (bid < 1856) { int rl = bid - 832,  z = rl >> 8;
    tr(Wq + (size_t)z * DD, WqkvT + (size_t)z * 3 * DD, 512, 512, 16, rl & 255, 0.125f); }
  else if (bid < 2880) { int rl = bid - 1856, z = rl >> 8;
    tr(Wk + (size_t)z * DD, WqkvT + (size_t)z * 3 * DD + DD, 512, 512, 16, rl & 255, 1.f); }
  else if (bid < 3904) { int rl = bid - 2880, z = rl >> 8;
    tr(Wv + (size_t)z * DD, WqkvT + (size_t)z * 3 * DD + 2 * DD, 512, 512, 16, rl & 255, 1.f); }
  else if (bid < 4928) { int rl = bid - 3904, z = rl >> 8;
    tr(Wo + (size_t)z * DD, WoT + (size_t)z * DD, 512, 512, 16, rl & 255, 1.f); }
  else if (bid < 9024) { int rl = bid - 4928, z = rl >> 10;
    tr(Wff1 + (size_t)z * FD, Wff1T + (size_t)z * FD, 512, 2048, 64, rl & 1023, 1.f); }
  else if (bid < 13120) { int rl = bid - 9024, z = rl >> 10;
    tr(Wff2 + (size_t)z * FD, Wff2T + (size_t)z * FD, 2048, 512, 16, rl & 1023, 1.f); }
  else if (bid < 13376) tr(Wg, WgT, 512, 512, 16, bid - 13120, 1.f);
  else if (bid < 23376) tr(Wout, WoutT, 512, 20000, 625, bid - 13376, 1.f);
  else {
    int i = (bid - 23376) * 256 + tid;           // L*3*512 = 6144 elems
    int d = i & 511, t2 = (i >> 9) % 3, l = i / (3 * 512);
    const float* src = (t2 == 0) ? bq : (t2 == 1) ? bk : bv;
    bqkv[i] = src[l * 512 + d] * (t2 == 0 ? 0.125f : 1.f);
  }
}

// fused: item embedding gather (padding_idx=0) -> cat[:,0:512]; audio cvt -> ab
__global__ void k_front(const int* __restrict__ ids, const float* __restrict__ tbl,
                        const float* __restrict__ audio,
                        __hip_bfloat16* __restrict__ cat, __hip_bfloat16* __restrict__ ab) {
  int n = blockIdx.x, t = threadIdx.x;
  int id = ids[n];
  const float* src = tbl + (size_t)id * 512;
  size_t dst = (size_t)n * 1024;
  float a0 = (id == 0) ? 0.f : src[t];
  float a1 = (id == 0) ? 0.f : src[t + 256];
  cat[dst + t] = __float2bfloat16(a0);
  cat[dst + t + 256] = __float2bfloat16(a1);
  if (t < 128) ab[(size_t)n * 128 + t] = __float2bfloat16(audio[(size_t)n * 128 + t]);
}

__global__ void k_ln(const float* __restrict__ x, const float* __restrict__ y,
                     const float* __restrict__ gam, const float* __restrict__ bet,
                     float* __restrict__ xout, __hip_bfloat16* __restrict__ xb) {
  int row = blockIdx.x, t = threadIdx.x;
  size_t base = (size_t)row * 512;
  float v0 = x[base + t], v1 = x[base + t + 256];
  if (y) { v0 += y[base + t]; v1 += y[base + t + 256]; }
  __shared__ float sm[4];
  float s = v0 + v1;
  for (int o = 32; o; o >>= 1) s += __shfl_xor(s, o);
  if ((t & 63) == 0) sm[t >> 6] = s;
  __syncthreads();
  float mean = (sm[0] + sm[1] + sm[2] + sm[3]) * (1.f / 512.f);
  __syncthreads();
  float d0 = v0 - mean, d1 = v1 - mean;
  float qq = d0 * d0 + d1 * d1;
  for (int o = 32; o; o >>= 1) qq += __shfl_xor(qq, o);
  if ((t & 63) == 0) sm[t >> 6] = qq;
  __syncthreads();
  float var = (sm[0] + sm[1] + sm[2] + sm[3]) * (1.f / 512.f);
  float rs = rsqrtf(var + 1e-5f);
  float o0 = d0 * rs * gam[t] + bet[t];
  float o1 = d1 * rs * gam[t + 256] + bet[t + 256];
  xout[base + t] = o0;
  xout[base + t + 256] = o1;
  xb[base + t] = __float2bfloat16(o0);
  xb[base + t + 256] = __float2bfloat16(o1);
}

// ---------------------------------------------------------------------------
extern "C" void kernel_launch(void* const* d_in, const int* in_sizes, int n_in,
                              void* d_out, int out_size, void* d_ws, size_t ws_size,
                              hipStream_t stream) {
  typedef __hip_bfloat16 bf;
  const int*   item_ids = (const int*)  d_in[0];
  const float* audio    = (const float*)d_in[1];
  const float* organic  = (const float*)d_in[2];
  const float* mask     = (const float*)d_in[3];
  const float* emb      = (const float*)d_in[4];
  const float* pe       = (const float*)d_in[5];
  const float* Wa1 = (const float*)d_in[6],  *ba1 = (const float*)d_in[7];
  const float* Wa2 = (const float*)d_in[8],  *ba2 = (const float*)d_in[9];
  const float* Wf  = (const float*)d_in[10], *bfb = (const float*)d_in[11];
  const float* Wq  = (const float*)d_in[12], *bq  = (const float*)d_in[13];
  const float* Wk  = (const float*)d_in[14], *bk  = (const float*)d_in[15];
  const float* Wv  = (const float*)d_in[16], *bv  = (const float*)d_in[17];
  const float* Wo  = (const float*)d_in[18], *bo  = (const float*)d_in[19];
  const float* ln1s = (const float*)d_in[22], *ln1b = (const float*)d_in[23];
  const float* ln2s = (const float*)d_in[24], *ln2b = (const float*)d_in[25];
  const float* Wff1 = (const float*)d_in[26], *bff1 = (const float*)d_in[27];
  const float* Wff2 = (const float*)d_in[28], *bff2 = (const float*)d_in[29];
  const float* lnOs = (const float*)d_in[30], *lnOb = (const float*)d_in[31];
  const float* Wg   = (const float*)d_in[32], *bg   = (const float*)d_in[33];
  const float* Wout = (const float*)d_in[34], *bout = (const float*)d_in[35];
  float* out = (float*)d_out;

  char* ws = (char*)d_ws;
  size_t off = 0;
  auto alloc = [&](size_t bytes) -> char* {
    char* p = ws + off;
    off = (off + bytes + 255) & ~(size_t)255;
    return p;
  };
  bf* Wa1T = (bf*)alloc((size_t)512 * 128 * 2);
  bf* Wa2T = (bf*)alloc((size_t)512 * 512 * 2);
  bf* WfT  = (bf*)alloc((size_t)512 * 1024 * 2);
  bf* WqkvT = (bf*)alloc((size_t)L_ * 3 * D_ * D_ * 2);   // [L][3*D][D]
  bf* WoT  = (bf*)alloc((size_t)L_ * D_ * D_ * 2);
  bf* Wff1T = (bf*)alloc((size_t)L_ * DFF_ * D_ * 2);
  bf* Wff2T = (bf*)alloc((size_t)L_ * D_ * DFF_ * 2);
  bf* WgT   = (bf*)alloc((size_t)512 * 512 * 2);
  bf* WoutT = (bf*)alloc((size_t)NOUT_PAD * 512 * 2);     // pad rows hold finite poison
  float* bqkv = (float*)alloc((size_t)L_ * 3 * 512 * 4);
  bf* ab    = (bf*)alloc((size_t)N_ * AD_ * 2);
  bf* cat   = (bf*)alloc((size_t)N_ * 1024 * 2);
  bf* ah    = (bf*)alloc((size_t)N_ * 512 * 2);
  float* xf = (float*)alloc((size_t)N_ * 512 * 4);
  bf* xb    = (bf*)alloc((size_t)N_ * 512 * 2);
  bf* qkv   = (bf*)alloc((size_t)3 * N_ * 512 * 2);       // [3][N][D] (v slot unused)
  bf* vt    = (bf*)alloc((size_t)B_ * H_ * DK_ * S_ * 2);
  bf* ctxb  = (bf*)alloc((size_t)N_ * 512 * 2);
  float* ybuf = (float*)alloc((size_t)N_ * 512 * 4);
  bf* ff1b  = (bf*)alloc((size_t)N_ * DFF_ * 2);
  bf* xg    = (bf*)alloc((size_t)N_ * 512 * 2);
  if (off > ws_size) return;  // loud failure (output stays poisoned)

  bf* qb = qkv;
  bf* kb = qkv + (size_t)N_ * 512;

  // ALL weight transposes + bias pack in one launch
  k_trans_all<<<23400, 256, 0, stream>>>(Wa1, Wa2, Wf, Wq, Wk, Wv, Wo, Wff1, Wff2,
      Wg, Wout, bq, bk, bv,
      Wa1T, Wa2T, WfT, WqkvT, WoT, Wff1T, Wff2T, WgT, WoutT, bqkv);

  // front-end
  k_front<<<N_, 256, 0, stream>>>(item_ids, emb, audio, cat, ab);
  gemm2<128, 64, 1, 1, 0><<<dim3(32, 8), 256, 0, stream>>>(ab, 128, Wa1T, 128,
      (void*)ah, 512, ba1, nullptr, nullptr, nullptr, 128, 512);
  gemm2<128, 64, 1, 0, 0><<<dim3(32, 8), 256, 0, stream>>>(ah, 512, Wa2T, 512,
      (void*)(cat + 512), 1024, ba2, nullptr, nullptr, nullptr, 512, 512);
  gemm2<128, 64, 2, 1, 0><<<dim3(32, 8), 256, 0, stream>>>(cat, 1024, WfT, 1024,
      (void*)xf, 512, bfb, (void*)xb, (const void*)pe, nullptr, 1024, 512);

  // layers
  for (int l = 0; l < L_; ++l) {
    // wide QKV, BN=128 (grid 32x12 = 384 blocks)
    gemm2<128, 128, 3, 0, 0><<<dim3(32, 12), 256, 0, stream>>>(xb, 512,
        WqkvT + (size_t)l * 3 * D_ * D_, 512, (void*)qkv, 512,
        bqkv + (size_t)l * 3 * 512, (void*)vt, nullptr, nullptr, 512, 1536);
    k_flash<<<dim3(8, B_ * H_), 256, 0, stream>>>(qb, kb, vt, mask, ctxb);
    // Wo + fused residual (xf) -> ybuf
    gemm2<128, 64, 5, 0, 0><<<dim3(32, 8), 256, 0, stream>>>(ctxb, 512,
        WoT + (size_t)l * D_ * D_, 512, (void*)ybuf, 512, bo + l * D_,
        nullptr, (const void*)xf, nullptr, 512, 512);
    k_ln<<<N_, 256, 0, stream>>>(ybuf, nullptr, ln1s + l * D_, ln1b + l * D_, xf, xb);
    gemm2<128, 128, 1, 1, 0><<<dim3(32, 16), 256, 0, stream>>>(xb, 512,
        Wff1T + (size_t)l * DFF_ * D_, 512, (void*)ff1b, 2048, bff1 + l * DFF_,
        nullptr, nullptr, nullptr, 512, 2048);
    // FF2 + fused residual (xf) -> ybuf
    gemm2<128, 64, 5, 0, 0><<<dim3(32, 8), 256, 0, stream>>>(ff1b, 2048,
        Wff2T + (size_t)l * D_ * DFF_, 2048, (void*)ybuf, 512, bff2 + l * D_,
        nullptr, (const void*)xf, nullptr, 2048, 512);
    k_ln<<<N_, 256, 0, stream>>>(ybuf, nullptr, ln2s + l * D_, ln2b + l * D_, xf, xb);
  }

  // final LN + gate(fused) + logits
  k_ln<<<N_, 256, 0, stream>>>(xf, nullptr, lnOs, lnOb, xf, xb);
  gemm2<128, 64, 4, 0, 0><<<dim3(32, 8), 256, 0, stream>>>(xb, 512, WgT, 512,
      (void*)xg, 512, bg, (const void*)xf, (const void*)organic,
      (const void*)(Wg + (size_t)512 * 512), 512, 512);
  // logits: 4096x20000x512 -> 256x256 BK=32 2-phase (staging traffic halved)
  gemm_big<256><<<dim3(16, 79), 512, 0, stream>>>(xg, 512, WoutT, 512,
      out, 20000, bout, 512, 20000);
}

// Round 12
// 839.560 us; speedup vs baseline: 1.1126x; 1.1126x over previous
//
#include <hip/hip_runtime.h>
#include <hip/hip_bf16.h>

typedef float f32x4 __attribute__((ext_vector_type(4)));
typedef __bf16 bf16x8 __attribute__((ext_vector_type(8)));

#define DEV __device__ __forceinline__

constexpr int B_ = 8, S_ = 512, D_ = 512, H_ = 8, L_ = 4, DFF_ = 2048, NI_ = 20000, AD_ = 128, DK_ = 64;
constexpr int N_ = B_ * S_;            // 4096 tokens
constexpr int NOUT_PAD = 20224;        // 79 * 256 (256-wide logits tiles)

DEV void gload_lds16(const void* g, void* l) {
  __builtin_amdgcn_global_load_lds((const __attribute__((address_space(1))) unsigned int*)g,
                                   (__attribute__((address_space(3))) unsigned int*)l, 16, 0, 0);
}

// m204 bijective XCD-chunk swizzle
DEV int xcd_swizzle(int bid, int nwg) {
  int q = nwg >> 3, r = nwg & 7;
  int x = bid & 7, idx = bid >> 3;
  int base = (x < r) ? x * (q + 1) : r * (q + 1) + (x - r) * q;
  return base + idx;
}

// ---------------------------------------------------------------------------
// Big-N streaming GEMM: 256x256 tile, BK=32, 8 waves (4Mx2N), 512 threads,
// 64 KB LDS, 2-phase. BK=32 swizzle ch ^= (row>>1)&3 (2-way = free).
// Plain cached loads AND plain (write-allocate) C-stores: NT f32 stores emit
// 64B partial lines -> +25-35% WRITE_SIZE (R8/R11 vs R3 ledger evidence).
// ---------------------------------------------------------------------------
__global__ __launch_bounds__(512)
void gemm_big(const __hip_bfloat16* __restrict__ A, int lda,
              const __hip_bfloat16* __restrict__ Bm, int ldb,
              float* __restrict__ C, int ldc,
              const float* __restrict__ bias, int K, int Ncols)
{
  constexpr int BN = 256, NJ = BN / 32;
  __shared__ __align__(16) unsigned short smA[2][256 * 32];
  __shared__ __align__(16) unsigned short smB[2][BN * 32];

  const int nwg = gridDim.x * gridDim.y;
  const int bid = blockIdx.y * gridDim.x + blockIdx.x;
  const int wgid = xcd_swizzle(bid, nwg);
  const int m0 = (wgid % gridDim.x) * 256, n0 = (wgid / gridDim.x) * BN;

  const int tid = threadIdx.x, wv = tid >> 6, lane = tid & 63;
  const int l15 = lane & 15, l4 = lane >> 4;
  const int wm = (wv >> 1) * 64, wn = (wv & 1) * (BN / 2);

  auto stage = [&](int buf, int k0) {
#pragma unroll
    for (int it = 0; it < 2; ++it) {               // A: 256 rows x 4 chunks
      int idx = it * 512 + tid, row = idx >> 2, c = idx & 3;
      int sc = c ^ ((row >> 1) & 3);
      gload_lds16((const void*)(A + (size_t)(m0 + row) * lda + k0 + sc * 8),
                  (void*)&smA[buf][(size_t)(it * 512 + wv * 64) * 8]);
    }
#pragma unroll
    for (int it = 0; it < BN / 128; ++it) {        // B: BN rows x 4 chunks
      int idx = it * 512 + tid, row = idx >> 2, c = idx & 3;
      int sc = c ^ ((row >> 1) & 3);
      gload_lds16((const void*)(Bm + (size_t)(n0 + row) * ldb + k0 + sc * 8),
                  (void*)&smB[buf][(size_t)(it * 512 + wv * 64) * 8]);
    }
  };

  f32x4 acc[4][NJ];
#pragma unroll
  for (int i = 0; i < 4; ++i)
#pragma unroll
    for (int j = 0; j < NJ; ++j) acc[i][j] = f32x4{0.f, 0.f, 0.f, 0.f};

  const int nk = K / 32;
  stage(0, 0);
  __syncthreads();

  int cur = 0;
  for (int t = 0; t < nk; ++t) {
    if (t + 1 < nk) stage(cur ^ 1, (t + 1) * 32);  // prefetch issue (async)

    bf16x8 af[4], bfr[NJ];
#pragma unroll
    for (int i = 0; i < 4; ++i) {
      int row = wm + i * 16 + l15;
      int ch = l4 ^ ((row >> 1) & 3);
      af[i] = *reinterpret_cast<const bf16x8*>(&smA[cur][row * 32 + ch * 8]);
    }
#pragma unroll
    for (int j = 0; j < NJ; ++j) {
      int row = wn + j * 16 + l15;
      int ch = l4 ^ ((row >> 1) & 3);
      bfr[j] = *reinterpret_cast<const bf16x8*>(&smB[cur][row * 32 + ch * 8]);
    }
    __builtin_amdgcn_s_setprio(1);
#pragma unroll
    for (int i = 0; i < 4; ++i)
#pragma unroll
      for (int j = 0; j < NJ; ++j)
        acc[i][j] = __builtin_amdgcn_mfma_f32_16x16x32_bf16(af[i], bfr[j], acc[i][j], 0, 0, 0);
    __builtin_amdgcn_s_setprio(0);
    __syncthreads();
    cur ^= 1;
  }

  // epilogue: C/D layout col = lane&15, row = (lane>>4)*4 + r
#pragma unroll
  for (int i = 0; i < 4; ++i) {
#pragma unroll
    for (int j = 0; j < NJ; ++j) {
#pragma unroll
      for (int r = 0; r < 4; ++r) {
        int row = m0 + wm + i * 16 + l4 * 4 + r;
        int col = n0 + wn + j * 16 + l15;
        if (col < Ncols)
          C[(size_t)row * ldc + col] = acc[i][j][r] + bias[col];
      }
    }
  }
}

// ---------------------------------------------------------------------------
// 2-phase bf16 GEMM, BK=64, T2 XOR-swizzled LDS (verified round 8).
// BM in {64,128}: 4 waves (2x2), per-wave (BM/2)x(BN/2).
// EPI: 0=f32 store, 1=bf16 store, 2=Wf+PE (write xf f32 + xb bf16),
//      3=QKV wide (q,k rows; v transposed into vt), 4=gate (sigmoid*xf->bf16),
//      5=f32 store + residual add from p2
// ---------------------------------------------------------------------------
template<int BM, int BN, int EPI, int ACT>
__global__ __launch_bounds__(256)
void gemm2(const __hip_bfloat16* __restrict__ A, int lda,
           const __hip_bfloat16* __restrict__ Bm, int ldb,
           void* __restrict__ Cv, int ldc,
           const float* __restrict__ bias,
           const void* __restrict__ p1, const void* __restrict__ p2,
           const void* __restrict__ p3,
           int K, int Ncols)
{
  constexpr int BK = 64;
  constexpr int MI = BM / 32, NJ = BN / 32;
  constexpr int LA = BM * BK / 2048, LB = BN * BK / 2048;
  __shared__ __align__(16) unsigned short smA[2][BM * BK];
  __shared__ __align__(16) unsigned short smB[2][BN * BK];

  const int nwg = gridDim.x * gridDim.y;
  const int bid = blockIdx.y * gridDim.x + blockIdx.x;
  const int wgid = xcd_swizzle(bid, nwg);
  const int m0 = (wgid % gridDim.x) * BM, n0 = (wgid / gridDim.x) * BN;

  const int tid = threadIdx.x, wv = tid >> 6, lane = tid & 63;
  const int l15 = lane & 15, l4 = lane >> 4;
  const int wm = (wv >> 1) * (BM / 2), wn = (wv & 1) * (BN / 2);

  auto stage = [&](int buf, int k0) {
#pragma unroll
    for (int it = 0; it < LA; ++it) {
      int idx = it * 256 + tid, row = idx >> 3, c = idx & 7;
      int sc = c ^ (row & 7);
      gload_lds16((const void*)(A + (size_t)(m0 + row) * lda + k0 + sc * 8),
                  (void*)&smA[buf][(size_t)(it * 256 + wv * 64) * 8]);
    }
#pragma unroll
    for (int it = 0; it < LB; ++it) {
      int idx = it * 256 + tid, row = idx >> 3, c = idx & 7;
      int sc = c ^ (row & 7);
      gload_lds16((const void*)(Bm + (size_t)(n0 + row) * ldb + k0 + sc * 8),
                  (void*)&smB[buf][(size_t)(it * 256 + wv * 64) * 8]);
    }
  };

  f32x4 acc[MI][NJ];
#pragma unroll
  for (int i = 0; i < MI; ++i)
#pragma unroll
    for (int j = 0; j < NJ; ++j) acc[i][j] = f32x4{0.f, 0.f, 0.f, 0.f};

  const int nk = K / BK;
  stage(0, 0);
  __syncthreads();

  int cur = 0;
  for (int t = 0; t < nk; ++t) {
    if (t + 1 < nk) stage(cur ^ 1, (t + 1) * BK);

    bf16x8 af[MI][2], bfr[NJ][2];
#pragma unroll
    for (int i = 0; i < MI; ++i)
#pragma unroll
      for (int kk = 0; kk < 2; ++kk) {
        int row = wm + i * 16 + l15;
        int ch = (kk * 4 + l4) ^ (row & 7);
        af[i][kk] = *reinterpret_cast<const bf16x8*>(&smA[cur][row * BK + ch * 8]);
      }
#pragma unroll
    for (int j = 0; j < NJ; ++j)
#pragma unroll
      for (int kk = 0; kk < 2; ++kk) {
        int row = wn + j * 16 + l15;
        int ch = (kk * 4 + l4) ^ (row & 7);
        bfr[j][kk] = *reinterpret_cast<const bf16x8*>(&smB[cur][row * BK + ch * 8]);
      }
    __builtin_amdgcn_s_setprio(1);
#pragma unroll
    for (int kk = 0; kk < 2; ++kk)
#pragma unroll
      for (int i = 0; i < MI; ++i)
#pragma unroll
        for (int j = 0; j < NJ; ++j)
          acc[i][j] = __builtin_amdgcn_mfma_f32_16x16x32_bf16(af[i][kk], bfr[j][kk], acc[i][j], 0, 0, 0);
    __builtin_amdgcn_s_setprio(0);
    __syncthreads();
    cur ^= 1;
  }

#pragma unroll
  for (int i = 0; i < MI; ++i) {
#pragma unroll
    for (int j = 0; j < NJ; ++j) {
#pragma unroll
      for (int r = 0; r < 4; ++r) {
        int row = m0 + wm + i * 16 + l4 * 4 + r;
        int col = n0 + wn + j * 16 + l15;
        if (col < Ncols) {
          float v = acc[i][j][r];
          if (bias) v += bias[col];
          if (ACT == 1) v = v > 0.f ? v : 0.f;
          if constexpr (EPI == 0) {
            ((float*)Cv)[(size_t)row * ldc + col] = v;
          } else if constexpr (EPI == 1) {
            ((__hip_bfloat16*)Cv)[(size_t)row * ldc + col] = __float2bfloat16(v);
          } else if constexpr (EPI == 2) {
            v += ((const float*)p2)[(size_t)(row & 511) * 512 + col];
            ((float*)Cv)[(size_t)row * ldc + col] = v;
            ((__hip_bfloat16*)p1)[(size_t)row * ldc + col] = __float2bfloat16(v);
          } else if constexpr (EPI == 3) {
            if (col < 1024) {
              ((__hip_bfloat16*)Cv)[(size_t)(col >> 9) * N_ * 512 + (size_t)row * 512 + (col & 511)] =
                  __float2bfloat16(v);
            } else {
              int hd = col - 1024, b = row >> 9, s = row & 511;
              ((__hip_bfloat16*)p1)[((size_t)(b * 8 + (hd >> 6)) * 64 + (hd & 63)) * 512 + s] =
                  __float2bfloat16(v);
            }
          } else if constexpr (EPI == 4) {
            float zz = v + ((const float*)p2)[row] * ((const float*)p3)[col];
            float sg = 1.f / (1.f + __expf(-zz));
            float xn = ((const float*)p1)[(size_t)row * 512 + col];
            ((__hip_bfloat16*)Cv)[(size_t)row * 512 + col] = __float2bfloat16(xn * sg);
          } else if constexpr (EPI == 5) {
            v += ((const float*)p2)[(size_t)row * 512 + col];   // residual
            ((float*)Cv)[(size_t)row * ldc + col] = v;
          }
        }
      }
    }
  }
}

// ---------------------------------------------------------------------------
// Fused flash attention (verified round 5).
// ---------------------------------------------------------------------------
__global__ __launch_bounds__(256)
void k_flash(const __hip_bfloat16* __restrict__ q, const __hip_bfloat16* __restrict__ k,
             const __hip_bfloat16* __restrict__ vt, const float* __restrict__ mask,
             __hip_bfloat16* __restrict__ ctx)
{
  __shared__ __align__(16) unsigned short Ql[64 * 64];
  __shared__ __align__(16) unsigned short Kl[2][64 * 64];
  __shared__ __align__(16) unsigned short Vl[2][64 * 64];
  __shared__ __align__(16) unsigned short Pl[4][16 * 64];

  const int qt = blockIdx.x, bh = blockIdx.y;
  const int b = bh >> 3, h = bh & 7;
  const int tid = threadIdx.x, wv = tid >> 6, lane = tid & 63;
  const int l15 = lane & 15, l4 = lane >> 4;
  const int q0 = qt * 64;

  const __hip_bfloat16* Qg = q + ((size_t)(b * 512 + q0) * 512) + h * 64;
  const __hip_bfloat16* Kg = k + ((size_t)(b * 512) * 512) + h * 64;
  const __hip_bfloat16* Vg = vt + ((size_t)bh * 64) * 512;
  const float* mk = mask + b * 512;

  auto stageQ = [&]() {
#pragma unroll
    for (int it = 0; it < 2; ++it) {
      int idx = it * 256 + wv * 64 + lane;
      int row = idx >> 3, c = idx & 7;
      gload_lds16((const void*)(Qg + (size_t)row * 512 + (c ^ (row & 7)) * 8),
                  (void*)&Ql[(it * 256 + wv * 64) * 8]);
    }
  };
  auto stageKV = [&](int buf, int kv0) {
#pragma unroll
    for (int it = 0; it < 2; ++it) {
      int idx = it * 256 + wv * 64 + lane;
      int row = idx >> 3, c = idx & 7;
      gload_lds16((const void*)(Kg + (size_t)(kv0 + row) * 512 + (c ^ (row & 7)) * 8),
                  (void*)&Kl[buf][(it * 256 + wv * 64) * 8]);
    }
#pragma unroll
    for (int it = 0; it < 2; ++it) {
      int idx = it * 256 + wv * 64 + lane;
      int row = idx >> 3, c = idx & 7;
      gload_lds16((const void*)(Vg + (size_t)row * 512 + kv0 + (c ^ (row & 7)) * 8),
                  (void*)&Vl[buf][(it * 256 + wv * 64) * 8]);
    }
  };

  stageQ();
  stageKV(0, 0);
  __syncthreads();

  bf16x8 aq[2];
#pragma unroll
  for (int kk = 0; kk < 2; ++kk) {
    int row = wv * 16 + l15;
    aq[kk] = *reinterpret_cast<const bf16x8*>(
        &Ql[row * 64 + (((kk * 4 + l4) ^ (row & 7)) * 8)]);
  }

  f32x4 accO[4];
  float mrun[4], lrun[4];
#pragma unroll
  for (int j = 0; j < 4; ++j) accO[j] = f32x4{0.f, 0.f, 0.f, 0.f};
#pragma unroll
  for (int r = 0; r < 4; ++r) { mrun[r] = -3e38f; lrun[r] = 0.f; }

  int cur = 0;
  for (int t = 0; t < 8; ++t) {
    if (t + 1 < 8) stageKV(cur ^ 1, (t + 1) * 64);
    const int kv0 = t * 64;

    f32x4 s[4];
#pragma unroll
    for (int j = 0; j < 4; ++j) s[j] = f32x4{0.f, 0.f, 0.f, 0.f};
#pragma unroll
    for (int kk = 0; kk < 2; ++kk) {
#pragma unroll
      for (int j = 0; j < 4; ++j) {
        int row = j * 16 + l15;
        bf16x8 bk = *reinterpret_cast<const bf16x8*>(
            &Kl[cur][row * 64 + (((kk * 4 + l4) ^ (row & 7)) * 8)]);
        s[j] = __builtin_amdgcn_mfma_f32_16x16x32_bf16(aq[kk], bk, s[j], 0, 0, 0);
      }
    }

#pragma unroll
    for (int j = 0; j < 4; ++j) {
      float mval = mk[kv0 + j * 16 + l15];
#pragma unroll
      for (int r = 0; r < 4; ++r)
        s[j][r] = (mval == 0.f) ? -1e30f : s[j][r];
    }

    float alpha[4];
#pragma unroll
    for (int r = 0; r < 4; ++r) {
      float v = fmaxf(fmaxf(s[0][r], s[1][r]), fmaxf(s[2][r], s[3][r]));
      v = fmaxf(v, __shfl_xor(v, 1));
      v = fmaxf(v, __shfl_xor(v, 2));
      v = fmaxf(v, __shfl_xor(v, 4));
      v = fmaxf(v, __shfl_xor(v, 8));
      float mn = fmaxf(mrun[r], v);
      alpha[r] = __expf(mrun[r] - mn);
      mrun[r] = mn;
    }
    float rs[4] = {0.f, 0.f, 0.f, 0.f};
#pragma unroll
    for (int j = 0; j < 4; ++j)
#pragma unroll
      for (int r = 0; r < 4; ++r) {
        float p = __expf(s[j][r] - mrun[r]);
        s[j][r] = p;
        rs[r] += p;
      }
#pragma unroll
    for (int r = 0; r < 4; ++r) {
      float v = rs[r];
      v += __shfl_xor(v, 1); v += __shfl_xor(v, 2);
      v += __shfl_xor(v, 4); v += __shfl_xor(v, 8);
      lrun[r] = lrun[r] * alpha[r] + v;
#pragma unroll
      for (int j = 0; j < 4; ++j) accO[j][r] *= alpha[r];
    }

#pragma unroll
    for (int j = 0; j < 4; ++j)
#pragma unroll
      for (int r = 0; r < 4; ++r) {
        int qrow = l4 * 4 + r, key = j * 16 + l15;
        __hip_bfloat16 hb = __float2bfloat16(s[j][r]);
        Pl[wv][qrow * 64 + (((key >> 3) ^ (qrow & 7)) * 8) + (key & 7)] =
            *reinterpret_cast<unsigned short*>(&hb);
      }

#pragma unroll
    for (int kc = 0; kc < 2; ++kc) {
      bf16x8 ap = *reinterpret_cast<const bf16x8*>(
          &Pl[wv][l15 * 64 + (((kc * 4 + l4) ^ (l15 & 7)) * 8)]);
#pragma unroll
      for (int j = 0; j < 4; ++j) {
        int row = j * 16 + l15;
        bf16x8 bv2 = *reinterpret_cast<const bf16x8*>(
            &Vl[cur][row * 64 + (((kc * 4 + l4) ^ (row & 7)) * 8)]);
        accO[j] = __builtin_amdgcn_mfma_f32_16x16x32_bf16(ap, bv2, accO[j], 0, 0, 0);
      }
    }
    __syncthreads();
    cur ^= 1;
  }

#pragma unroll
  for (int r = 0; r < 4; ++r) {
    float inv = lrun[r] > 0.f ? 1.f / lrun[r] : 0.f;
#pragma unroll
    for (int j = 0; j < 4; ++j) {
      int row = q0 + wv * 16 + l4 * 4 + r;
      int col = h * 64 + j * 16 + l15;
      ctx[(size_t)(b * 512 + row) * 512 + col] = __float2bfloat16(accO[j][r] * inv);
    }
  }
}

// ---------------------------------------------------------------------------
// ALL weight transposes + bias pack in ONE launch. 23400 blocks x 256 thr.
// ---------------------------------------------------------------------------
__global__ __launch_bounds__(256)
void k_trans_all(const float* __restrict__ Wa1, const float* __restrict__ Wa2,
                 const float* __restrict__ Wf, const float* __restrict__ Wq,
                 const float* __restrict__ Wk, const float* __restrict__ Wv,
                 const float* __restrict__ Wo, const float* __restrict__ Wff1,
                 const float* __restrict__ Wff2, const float* __restrict__ Wg,
                 const float* __restrict__ Wout,
                 const float* __restrict__ bq, const float* __restrict__ bk,
                 const float* __restrict__ bv,
                 __hip_bfloat16* Wa1T, __hip_bfloat16* Wa2T, __hip_bfloat16* WfT,
                 __hip_bfloat16* WqkvT, __hip_bfloat16* WoT, __hip_bfloat16* Wff1T,
                 __hip_bfloat16* Wff2T, __hip_bfloat16* WgT, __hip_bfloat16* WoutT,
                 float* bqkv)
{
  __shared__ float tile[32][33];
  const int bid = blockIdx.x, tid = threadIdx.x;
  const int tx = tid & 31, ty = tid >> 5;

  auto tr = [&](const float* ip, __hip_bfloat16* op, int K, int N, int NTX,
                int t, float scale) {
    int bx = t % NTX, by = t / NTX;
    int n0 = bx * 32, k0 = by * 32;
#pragma unroll
    for (int r = 0; r < 4; ++r) {
      int k = k0 + ty + r * 8, n = n0 + tx;
      if (k < K && n < N) tile[ty + r * 8][tx] = ip[(size_t)k * N + n];
    }
    __syncthreads();
#pragma unroll
    for (int r = 0; r < 4; ++r) {
      int n = n0 + ty + r * 8, k = k0 + tx;
      if (n < N && k < K) op[(size_t)n * K + k] = __float2bfloat16(tile[tx][ty + r * 8] * scale);
    }
  };

  constexpr int DD = 512 * 512, FD = 512 * 2048;
  if (bid < 64)        tr(Wa1, Wa1T, 128, 512, 16, bid, 1.f);
  else if (bid < 320)  tr(Wa2, Wa2T, 512, 512, 16, bid - 64, 1.f);
  else if (bid < 832)  tr(Wf, WfT, 1024, 512, 16, bid - 320, 1.f);
  else if (bid < 1856) { int rl = bid - 832,  z = rl >> 8;
    tr(Wq + (size_t)z * DD, WqkvT + (size_t)z * 3 * DD, 512, 512, 16, rl & 255, 0.125f); }
  else if (bid < 2880) { int rl = bid - 1856, z = rl >> 8;
    tr(Wk + (size_t)z * DD, WqkvT + (size_t)z * 3 * DD + DD, 512, 512, 16, rl & 255, 1.f); }
  else if (bid < 3904) { int rl = bid - 2880, z = rl >> 8;
    tr(Wv + (size_t)z * DD, WqkvT + (size_t)z * 3 * DD + 2 * DD, 512, 512, 16, rl & 255, 1.f); }
  else if (bid < 4928) { int rl = bid - 3904, z = rl >> 8;
    tr(Wo + (size_t)z * DD, WoT + (size_t)z * DD, 512, 512, 16, rl & 255, 1.f); }
  else if (bid < 9024) { int rl = bid - 4928, z = rl >> 10;
    tr(Wff1 + (size_t)z * FD, Wff1T + (size_t)z * FD, 512, 2048, 64, rl & 1023, 1.f); }
  else if (bid < 13120) { int rl = bid - 9024, z = rl >> 10;
    tr(Wff2 + (size_t)z * FD, Wff2T + (size_t)z * FD, 2048, 512, 16, rl & 1023, 1.f); }
  else if (bid < 13376) tr(Wg, WgT, 512, 512, 16, bid - 13120, 1.f);
  else if (bid < 23376) tr(Wout, WoutT, 512, 20000, 625, bid - 13376, 1.f);
  else {
    int i = (bid - 23376) * 256 + tid;           // L*3*512 = 6144 elems
    int d = i & 511, t2 = (i >> 9) % 3, l = i / (3 * 512);
    const float* src = (t2 == 0) ? bq : (t2 == 1) ? bk : bv;
    bqkv[i] = src[l * 512 + d] * (t2 == 0 ? 0.125f : 1.f);
  }
}

// fused: item embedding gather (padding_idx=0) -> cat[:,0:512]; audio cvt -> ab
__global__ void k_front(const int* __restrict__ ids, const float* __restrict__ tbl,
                        const float* __restrict__ audio,
                        __hip_bfloat16* __restrict__ cat, __hip_bfloat16* __restrict__ ab) {
  int n = blockIdx.x, t = threadIdx.x;
  int id = ids[n];
  const float* src = tbl + (size_t)id * 512;
  size_t dst = (size_t)n * 1024;
  float a0 = (id == 0) ? 0.f : src[t];
  float a1 = (id == 0) ? 0.f : src[t + 256];
  cat[dst + t] = __float2bfloat16(a0);
  cat[dst + t + 256] = __float2bfloat16(a1);
  if (t < 128) ab[(size_t)n * 128 + t] = __float2bfloat16(audio[(size_t)n * 128 + t]);
}

__global__ void k_ln(const float* __restrict__ x, const float* __restrict__ y,
                     const float* __restrict__ gam, const float* __restrict__ bet,
                     float* __restrict__ xout, __hip_bfloat16* __restrict__ xb) {
  int row = blockIdx.x, t = threadIdx.x;
  size_t base = (size_t)row * 512;
  float v0 = x[base + t], v1 = x[base + t + 256];
  if (y) { v0 += y[base + t]; v1 += y[base + t + 256]; }
  __shared__ float sm[4];
  float s = v0 + v1;
  for (int o = 32; o; o >>= 1) s += __shfl_xor(s, o);
  if ((t & 63) == 0) sm[t >> 6] = s;
  __syncthreads();
  float mean = (sm[0] + sm[1] + sm[2] + sm[3]) * (1.f / 512.f);
  __syncthreads();
  float d0 = v0 - mean, d1 = v1 - mean;
  float qq = d0 * d0 + d1 * d1;
  for (int o = 32; o; o >>= 1) qq += __shfl_xor(qq, o);
  if ((t & 63) == 0) sm[t >> 6] = qq;
  __syncthreads();
  float var = (sm[0] + sm[1] + sm[2] + sm[3]) * (1.f / 512.f);
  float rs = rsqrtf(var + 1e-5f);
  float o0 = d0 * rs * gam[t] + bet[t];
  float o1 = d1 * rs * gam[t + 256] + bet[t + 256];
  xout[base + t] = o0;
  xout[base + t + 256] = o1;
  xb[base + t] = __float2bfloat16(o0);
  xb[base + t + 256] = __float2bfloat16(o1);
}

// ---------------------------------------------------------------------------
extern "C" void kernel_launch(void* const* d_in, const int* in_sizes, int n_in,
                              void* d_out, int out_size, void* d_ws, size_t ws_size,
                              hipStream_t stream) {
  typedef __hip_bfloat16 bf;
  const int*   item_ids = (const int*)  d_in[0];
  const float* audio    = (const float*)d_in[1];
  const float* organic  = (const float*)d_in[2];
  const float* mask     = (const float*)d_in[3];
  const float* emb      = (const float*)d_in[4];
  const float* pe       = (const float*)d_in[5];
  const float* Wa1 = (const float*)d_in[6],  *ba1 = (const float*)d_in[7];
  const float* Wa2 = (const float*)d_in[8],  *ba2 = (const float*)d_in[9];
  const float* Wf  = (const float*)d_in[10], *bfb = (const float*)d_in[11];
  const float* Wq  = (const float*)d_in[12], *bq  = (const float*)d_in[13];
  const float* Wk  = (const float*)d_in[14], *bk  = (const float*)d_in[15];
  const float* Wv  = (const float*)d_in[16], *bv  = (const float*)d_in[17];
  const float* Wo  = (const float*)d_in[18], *bo  = (const float*)d_in[19];
  const float* ln1s = (const float*)d_in[22], *ln1b = (const float*)d_in[23];
  const float* ln2s = (const float*)d_in[24], *ln2b = (const float*)d_in[25];
  const float* Wff1 = (const float*)d_in[26], *bff1 = (const float*)d_in[27];
  const float* Wff2 = (const float*)d_in[28], *bff2 = (const float*)d_in[29];
  const float* lnOs = (const float*)d_in[30], *lnOb = (const float*)d_in[31];
  const float* Wg   = (const float*)d_in[32], *bg   = (const float*)d_in[33];
  const float* Wout = (const float*)d_in[34], *bout = (const float*)d_in[35];
  float* out = (float*)d_out;

  char* ws = (char*)d_ws;
  size_t off = 0;
  auto alloc = [&](size_t bytes) -> char* {
    char* p = ws + off;
    off = (off + bytes + 255) & ~(size_t)255;
    return p;
  };
  bf* Wa1T = (bf*)alloc((size_t)512 * 128 * 2);
  bf* Wa2T = (bf*)alloc((size_t)512 * 512 * 2);
  bf* WfT  = (bf*)alloc((size_t)512 * 1024 * 2);
  bf* WqkvT = (bf*)alloc((size_t)L_ * 3 * D_ * D_ * 2);   // [L][3*D][D]
  bf* WoT  = (bf*)alloc((size_t)L_ * D_ * D_ * 2);
  bf* Wff1T = (bf*)alloc((size_t)L_ * DFF_ * D_ * 2);
  bf* Wff2T = (bf*)alloc((size_t)L_ * D_ * DFF_ * 2);
  bf* WgT   = (bf*)alloc((size_t)512 * 512 * 2);
  bf* WoutT = (bf*)alloc((size_t)NOUT_PAD * 512 * 2);     // pad rows hold finite poison
  float* bqkv = (float*)alloc((size_t)L_ * 3 * 512 * 4);
  bf* ab    = (bf*)alloc((size_t)N_ * AD_ * 2);
  bf* cat   = (bf*)alloc((size_t)N_ * 1024 * 2);
  bf* ah    = (bf*)alloc((size_t)N_ * 512 * 2);
  float* xf = (float*)alloc((size_t)N_ * 512 * 4);
  bf* xb    = (bf*)alloc((size_t)N_ * 512 * 2);
  bf* qkv   = (bf*)alloc((size_t)3 * N_ * 512 * 2);       // [3][N][D] (v slot unused)
  bf* vt    = (bf*)alloc((size_t)B_ * H_ * DK_ * S_ * 2);
  bf* ctxb  = (bf*)alloc((size_t)N_ * 512 * 2);
  float* ybuf = (float*)alloc((size_t)N_ * 512 * 4);
  bf* ff1b  = (bf*)alloc((size_t)N_ * DFF_ * 2);
  bf* xg    = (bf*)alloc((size_t)N_ * 512 * 2);
  if (off > ws_size) return;  // loud failure (output stays poisoned)

  bf* qb = qkv;
  bf* kb = qkv + (size_t)N_ * 512;

  // ALL weight transposes + bias pack in one launch
  k_trans_all<<<23400, 256, 0, stream>>>(Wa1, Wa2, Wf, Wq, Wk, Wv, Wo, Wff1, Wff2,
      Wg, Wout, bq, bk, bv,
      Wa1T, Wa2T, WfT, WqkvT, WoT, Wff1T, Wff2T, WgT, WoutT, bqkv);

  // front-end
  k_front<<<N_, 256, 0, stream>>>(item_ids, emb, audio, cat, ab);
  gemm2<128, 64, 1, 1><<<dim3(32, 8), 256, 0, stream>>>(ab, 128, Wa1T, 128,
      (void*)ah, 512, ba1, nullptr, nullptr, nullptr, 128, 512);
  gemm2<64, 64, 1, 0><<<dim3(64, 8), 256, 0, stream>>>(ah, 512, Wa2T, 512,
      (void*)(cat + 512), 1024, ba2, nullptr, nullptr, nullptr, 512, 512);
  gemm2<64, 64, 2, 1><<<dim3(64, 8), 256, 0, stream>>>(cat, 1024, WfT, 1024,
      (void*)xf, 512, bfb, (void*)xb, (const void*)pe, nullptr, 1024, 512);

  // layers
  for (int l = 0; l < L_; ++l) {
    // wide QKV, BN=64 (grid 32x24 = 768 blocks, 3 blocks/CU)
    gemm2<128, 64, 3, 0><<<dim3(32, 24), 256, 0, stream>>>(xb, 512,
        WqkvT + (size_t)l * 3 * D_ * D_, 512, (void*)qkv, 512,
        bqkv + (size_t)l * 3 * 512, (void*)vt, nullptr, nullptr, 512, 1536);
    k_flash<<<dim3(8, B_ * H_), 256, 0, stream>>>(qb, kb, vt, mask, ctxb);
    // Wo + fused residual (xf) -> ybuf : BM=64 for 2x block parallelism
    gemm2<64, 64, 5, 0><<<dim3(64, 8), 256, 0, stream>>>(ctxb, 512,
        WoT + (size_t)l * D_ * D_, 512, (void*)ybuf, 512, bo + l * D_,
        nullptr, (const void*)xf, nullptr, 512, 512);
    k_ln<<<N_, 256, 0, stream>>>(ybuf, nullptr, ln1s + l * D_, ln1b + l * D_, xf, xb);
    gemm2<128, 128, 1, 1><<<dim3(32, 16), 256, 0, stream>>>(xb, 512,
        Wff1T + (size_t)l * DFF_ * D_, 512, (void*)ff1b, 2048, bff1 + l * DFF_,
        nullptr, nullptr, nullptr, 512, 2048);
    // FF2 + fused residual (xf) -> ybuf : BM=64
    gemm2<64, 64, 5, 0><<<dim3(64, 8), 256, 0, stream>>>(ff1b, 2048,
        Wff2T + (size_t)l * D_ * DFF_, 2048, (void*)ybuf, 512, bff2 + l * D_,
        nullptr, (const void*)xf, nullptr, 2048, 512);
    k_ln<<<N_, 256, 0, stream>>>(ybuf, nullptr, ln2s + l * D_, ln2b + l * D_, xf, xb);
  }

  // final LN + gate(fused) + logits
  k_ln<<<N_, 256, 0, stream>>>(xf, nullptr, lnOs, lnOb, xf, xb);
  gemm2<64, 64, 4, 0><<<dim3(64, 8), 256, 0, stream>>>(xb, 512, WgT, 512,
      (void*)xg, 512, bg, (const void*)xf, (const void*)organic,
      (const void*)(Wg + (size_t)512 * 512), 512, 512);
  // logits: 4096x20000x512 -> 256x256 BK=32 2-phase, plain cached f32 stores
  gemm_big<<<dim3(16, 79), 512, 0, stream>>>(xg, 512, WoutT, 512,
      out, 20000, bout, 512, 20000);
}

// Round 13
// 791.376 us; speedup vs baseline: 1.1803x; 1.0609x over previous
//
#include <hip/hip_runtime.h>
#include <hip/hip_bf16.h>

typedef float f32x4 __attribute__((ext_vector_type(4)));
typedef __bf16 bf16x8 __attribute__((ext_vector_type(8)));

#define DEV __device__ __forceinline__

constexpr int B_ = 8, S_ = 512, D_ = 512, H_ = 8, L_ = 4, DFF_ = 2048, NI_ = 20000, AD_ = 128, DK_ = 64;
constexpr int N_ = B_ * S_;            // 4096 tokens
constexpr int NOUT_PAD = 20224;        // 79 * 256 (256-wide logits tiles)

DEV void gload_lds16(const void* g, void* l) {
  __builtin_amdgcn_global_load_lds((const __attribute__((address_space(1))) unsigned int*)g,
                                   (__attribute__((address_space(3))) unsigned int*)l, 16, 0, 0);
}

// m204 bijective XCD-chunk swizzle
DEV int xcd_swizzle(int bid, int nwg) {
  int q = nwg >> 3, r = nwg & 7;
  int x = bid & 7, idx = bid >> 3;
  int base = (x < r) ? x * (q + 1) : r * (q + 1) + (x - r) * q;
  return base + idx;
}

// ---------------------------------------------------------------------------
// Big-N streaming GEMM: 256x256 tile, BK=32, 8 waves (4Mx2N), 512 threads,
// 64 KB LDS, 2-phase. BK=32 swizzle ch ^= (row>>1)&3 (2-way = free).
// Plain cached loads (NT loads defeat inter-block B reuse -- R9 lesson).
// Epilogue: LDS-bounce -> f32x4 NT stores, 8 lanes = one full 128B line
// (row stride 80000B is 128B-aligned). NT avoids L2 write-allocate pollution
// (keeps B panel resident) WITHOUT the partial-line waste of fragment-order
// NT stores (R8/R11: WRITE 400-443 MB vs 330 compulsory).
// ---------------------------------------------------------------------------
__global__ __launch_bounds__(512)
void gemm_big(const __hip_bfloat16* __restrict__ A, int lda,
              const __hip_bfloat16* __restrict__ Bm, int ldb,
              float* __restrict__ C, int ldc,
              const float* __restrict__ bias, int K, int Ncols)
{
  constexpr int BN = 256, NJ = BN / 32;
  __shared__ __align__(16) unsigned short smA[2][256 * 32];
  __shared__ __align__(16) unsigned short smB[2][BN * 32];

  const int nwg = gridDim.x * gridDim.y;
  const int bid = blockIdx.y * gridDim.x + blockIdx.x;
  const int wgid = xcd_swizzle(bid, nwg);
  const int m0 = (wgid % gridDim.x) * 256, n0 = (wgid / gridDim.x) * BN;

  const int tid = threadIdx.x, wv = tid >> 6, lane = tid & 63;
  const int l15 = lane & 15, l4 = lane >> 4;
  const int wm = (wv >> 1) * 64, wn = (wv & 1) * (BN / 2);

  auto stage = [&](int buf, int k0) {
#pragma unroll
    for (int it = 0; it < 2; ++it) {               // A: 256 rows x 4 chunks
      int idx = it * 512 + tid, row = idx >> 2, c = idx & 3;
      int sc = c ^ ((row >> 1) & 3);
      gload_lds16((const void*)(A + (size_t)(m0 + row) * lda + k0 + sc * 8),
                  (void*)&smA[buf][(size_t)(it * 512 + wv * 64) * 8]);
    }
#pragma unroll
    for (int it = 0; it < BN / 128; ++it) {        // B: BN rows x 4 chunks
      int idx = it * 512 + tid, row = idx >> 2, c = idx & 3;
      int sc = c ^ ((row >> 1) & 3);
      gload_lds16((const void*)(Bm + (size_t)(n0 + row) * ldb + k0 + sc * 8),
                  (void*)&smB[buf][(size_t)(it * 512 + wv * 64) * 8]);
    }
  };

  f32x4 acc[4][NJ];
#pragma unroll
  for (int i = 0; i < 4; ++i)
#pragma unroll
    for (int j = 0; j < NJ; ++j) acc[i][j] = f32x4{0.f, 0.f, 0.f, 0.f};

  const int nk = K / 32;
  stage(0, 0);
  __syncthreads();

  int cur = 0;
  for (int t = 0; t < nk; ++t) {
    if (t + 1 < nk) stage(cur ^ 1, (t + 1) * 32);  // prefetch issue (async)

    bf16x8 af[4], bfr[NJ];
#pragma unroll
    for (int i = 0; i < 4; ++i) {
      int row = wm + i * 16 + l15;
      int ch = l4 ^ ((row >> 1) & 3);
      af[i] = *reinterpret_cast<const bf16x8*>(&smA[cur][row * 32 + ch * 8]);
    }
#pragma unroll
    for (int j = 0; j < NJ; ++j) {
      int row = wn + j * 16 + l15;
      int ch = l4 ^ ((row >> 1) & 3);
      bfr[j] = *reinterpret_cast<const bf16x8*>(&smB[cur][row * 32 + ch * 8]);
    }
    __builtin_amdgcn_s_setprio(1);
#pragma unroll
    for (int i = 0; i < 4; ++i)
#pragma unroll
      for (int j = 0; j < NJ; ++j)
        acc[i][j] = __builtin_amdgcn_mfma_f32_16x16x32_bf16(af[i], bfr[j], acc[i][j], 0, 0, 0);
    __builtin_amdgcn_s_setprio(0);
    __syncthreads();
    cur ^= 1;
  }

  // ---- LDS-bounce epilogue ----
  // fragment layout: col = lane&15, row = (lane>>4)*4 + r  [m89/m91 verified]
  // even waves own cols [0,128) -> bufE; odd waves cols [128,256) -> bufO.
  float* bufE = (float*)&smA[0][0];    // 32 KB = [256][32] f32
  float* bufO = (float*)&smB[0][0];    // 32 KB
  const int half = wv & 1;
#pragma unroll
  for (int p = 0; p < 4; ++p) {
    __syncthreads();                   // previous chunk fully stored / K-loop done
    float* dst = half ? bufO : bufE;
#pragma unroll
    for (int jj = 0; jj < 2; ++jj) {
      int j = 2 * p + jj;
#pragma unroll
      for (int i = 0; i < 4; ++i) {
#pragma unroll
        for (int r = 0; r < 4; ++r) {
          int rowl = wm + i * 16 + l4 * 4 + r;
          int coll = jj * 16 + l15;
          int gc = n0 + half * 128 + p * 32 + coll;
          float bv = (gc < Ncols) ? bias[gc] : 0.f;
          dst[rowl * 32 + coll] = acc[i][j][r] + bv;
        }
      }
    }
    __syncthreads();
    // stream both buffers out: thread -> f32x4; 8 consecutive threads = 128B line
#pragma unroll
    for (int rr = 0; rr < 4; ++rr) {
      int row = rr * 64 + (tid >> 3);
      int coll = (tid & 7) * 4;
      int gcE = n0 + p * 32 + coll;
      int gcO = n0 + 128 + p * 32 + coll;
      f32x4 vE = *(const f32x4*)&bufE[row * 32 + coll];
      f32x4 vO = *(const f32x4*)&bufO[row * 32 + coll];
      if (gcE < Ncols)   // Ncols%4==0, gc%4==0 -> whole vector in-bounds
        __builtin_nontemporal_store(vE, (f32x4*)&C[(size_t)(m0 + row) * ldc + gcE]);
      if (gcO < Ncols)
        __builtin_nontemporal_store(vO, (f32x4*)&C[(size_t)(m0 + row) * ldc + gcO]);
    }
  }
}

// ---------------------------------------------------------------------------
// 2-phase bf16 GEMM, BK=64, T2 XOR-swizzled LDS (verified round 8).
// BM in {64,128}: 4 waves (2x2), per-wave (BM/2)x(BN/2).
// EPI: 0=f32 store, 1=bf16 store, 2=Wf+PE (write xf f32 + xb bf16),
//      3=QKV wide (q,k rows; v transposed into vt), 4=gate (sigmoid*xf->bf16),
//      5=f32 store + residual add from p2
// ---------------------------------------------------------------------------
template<int BM, int BN, int EPI, int ACT>
__global__ __launch_bounds__(256)
void gemm2(const __hip_bfloat16* __restrict__ A, int lda,
           const __hip_bfloat16* __restrict__ Bm, int ldb,
           void* __restrict__ Cv, int ldc,
           const float* __restrict__ bias,
           const void* __restrict__ p1, const void* __restrict__ p2,
           const void* __restrict__ p3,
           int K, int Ncols)
{
  constexpr int BK = 64;
  constexpr int MI = BM / 32, NJ = BN / 32;
  constexpr int LA = BM * BK / 2048, LB = BN * BK / 2048;
  __shared__ __align__(16) unsigned short smA[2][BM * BK];
  __shared__ __align__(16) unsigned short smB[2][BN * BK];

  const int nwg = gridDim.x * gridDim.y;
  const int bid = blockIdx.y * gridDim.x + blockIdx.x;
  const int wgid = xcd_swizzle(bid, nwg);
  const int m0 = (wgid % gridDim.x) * BM, n0 = (wgid / gridDim.x) * BN;

  const int tid = threadIdx.x, wv = tid >> 6, lane = tid & 63;
  const int l15 = lane & 15, l4 = lane >> 4;
  const int wm = (wv >> 1) * (BM / 2), wn = (wv & 1) * (BN / 2);

  auto stage = [&](int buf, int k0) {
#pragma unroll
    for (int it = 0; it < LA; ++it) {
      int idx = it * 256 + tid, row = idx >> 3, c = idx & 7;
      int sc = c ^ (row & 7);
      gload_lds16((const void*)(A + (size_t)(m0 + row) * lda + k0 + sc * 8),
                  (void*)&smA[buf][(size_t)(it * 256 + wv * 64) * 8]);
    }
#pragma unroll
    for (int it = 0; it < LB; ++it) {
      int idx = it * 256 + tid, row = idx >> 3, c = idx & 7;
      int sc = c ^ (row & 7);
      gload_lds16((const void*)(Bm + (size_t)(n0 + row) * ldb + k0 + sc * 8),
                  (void*)&smB[buf][(size_t)(it * 256 + wv * 64) * 8]);
    }
  };

  f32x4 acc[MI][NJ];
#pragma unroll
  for (int i = 0; i < MI; ++i)
#pragma unroll
    for (int j = 0; j < NJ; ++j) acc[i][j] = f32x4{0.f, 0.f, 0.f, 0.f};

  const int nk = K / BK;
  stage(0, 0);
  __syncthreads();

  int cur = 0;
  for (int t = 0; t < nk; ++t) {
    if (t + 1 < nk) stage(cur ^ 1, (t + 1) * BK);

    bf16x8 af[MI][2], bfr[NJ][2];
#pragma unroll
    for (int i = 0; i < MI; ++i)
#pragma unroll
      for (int kk = 0; kk < 2; ++kk) {
        int row = wm + i * 16 + l15;
        int ch = (kk * 4 + l4) ^ (row & 7);
        af[i][kk] = *reinterpret_cast<const bf16x8*>(&smA[cur][row * BK + ch * 8]);
      }
#pragma unroll
    for (int j = 0; j < NJ; ++j)
#pragma unroll
      for (int kk = 0; kk < 2; ++kk) {
        int row = wn + j * 16 + l15;
        int ch = (kk * 4 + l4) ^ (row & 7);
        bfr[j][kk] = *reinterpret_cast<const bf16x8*>(&smB[cur][row * BK + ch * 8]);
      }
    __builtin_amdgcn_s_setprio(1);
#pragma unroll
    for (int kk = 0; kk < 2; ++kk)
#pragma unroll
      for (int i = 0; i < MI; ++i)
#pragma unroll
        for (int j = 0; j < NJ; ++j)
          acc[i][j] = __builtin_amdgcn_mfma_f32_16x16x32_bf16(af[i][kk], bfr[j][kk], acc[i][j], 0, 0, 0);
    __builtin_amdgcn_s_setprio(0);
    __syncthreads();
    cur ^= 1;
  }

#pragma unroll
  for (int i = 0; i < MI; ++i) {
#pragma unroll
    for (int j = 0; j < NJ; ++j) {
#pragma unroll
      for (int r = 0; r < 4; ++r) {
        int row = m0 + wm + i * 16 + l4 * 4 + r;
        int col = n0 + wn + j * 16 + l15;
        if (col < Ncols) {
          float v = acc[i][j][r];
          if (bias) v += bias[col];
          if (ACT == 1) v = v > 0.f ? v : 0.f;
          if constexpr (EPI == 0) {
            ((float*)Cv)[(size_t)row * ldc + col] = v;
          } else if constexpr (EPI == 1) {
            ((__hip_bfloat16*)Cv)[(size_t)row * ldc + col] = __float2bfloat16(v);
          } else if constexpr (EPI == 2) {
            v += ((const float*)p2)[(size_t)(row & 511) * 512 + col];
            ((float*)Cv)[(size_t)row * ldc + col] = v;
            ((__hip_bfloat16*)p1)[(size_t)row * ldc + col] = __float2bfloat16(v);
          } else if constexpr (EPI == 3) {
            if (col < 1024) {
              ((__hip_bfloat16*)Cv)[(size_t)(col >> 9) * N_ * 512 + (size_t)row * 512 + (col & 511)] =
                  __float2bfloat16(v);
            } else {
              int hd = col - 1024, b = row >> 9, s = row & 511;
              ((__hip_bfloat16*)p1)[((size_t)(b * 8 + (hd >> 6)) * 64 + (hd & 63)) * 512 + s] =
                  __float2bfloat16(v);
            }
          } else if constexpr (EPI == 4) {
            float zz = v + ((const float*)p2)[row] * ((const float*)p3)[col];
            float sg = 1.f / (1.f + __expf(-zz));
            float xn = ((const float*)p1)[(size_t)row * 512 + col];
            ((__hip_bfloat16*)Cv)[(size_t)row * 512 + col] = __float2bfloat16(xn * sg);
          } else if constexpr (EPI == 5) {
            v += ((const float*)p2)[(size_t)row * 512 + col];   // residual
            ((float*)Cv)[(size_t)row * ldc + col] = v;
          }
        }
      }
    }
  }
}

// ---------------------------------------------------------------------------
// Fused flash attention (verified round 5).
// ---------------------------------------------------------------------------
__global__ __launch_bounds__(256)
void k_flash(const __hip_bfloat16* __restrict__ q, const __hip_bfloat16* __restrict__ k,
             const __hip_bfloat16* __restrict__ vt, const float* __restrict__ mask,
             __hip_bfloat16* __restrict__ ctx)
{
  __shared__ __align__(16) unsigned short Ql[64 * 64];
  __shared__ __align__(16) unsigned short Kl[2][64 * 64];
  __shared__ __align__(16) unsigned short Vl[2][64 * 64];
  __shared__ __align__(16) unsigned short Pl[4][16 * 64];

  const int qt = blockIdx.x, bh = blockIdx.y;
  const int b = bh >> 3, h = bh & 7;
  const int tid = threadIdx.x, wv = tid >> 6, lane = tid & 63;
  const int l15 = lane & 15, l4 = lane >> 4;
  const int q0 = qt * 64;

  const __hip_bfloat16* Qg = q + ((size_t)(b * 512 + q0) * 512) + h * 64;
  const __hip_bfloat16* Kg = k + ((size_t)(b * 512) * 512) + h * 64;
  const __hip_bfloat16* Vg = vt + ((size_t)bh * 64) * 512;
  const float* mk = mask + b * 512;

  auto stageQ = [&]() {
#pragma unroll
    for (int it = 0; it < 2; ++it) {
      int idx = it * 256 + wv * 64 + lane;
      int row = idx >> 3, c = idx & 7;
      gload_lds16((const void*)(Qg + (size_t)row * 512 + (c ^ (row & 7)) * 8),
                  (void*)&Ql[(it * 256 + wv * 64) * 8]);
    }
  };
  auto stageKV = [&](int buf, int kv0) {
#pragma unroll
    for (int it = 0; it < 2; ++it) {
      int idx = it * 256 + wv * 64 + lane;
      int row = idx >> 3, c = idx & 7;
      gload_lds16((const void*)(Kg + (size_t)(kv0 + row) * 512 + (c ^ (row & 7)) * 8),
                  (void*)&Kl[buf][(it * 256 + wv * 64) * 8]);
    }
#pragma unroll
    for (int it = 0; it < 2; ++it) {
      int idx = it * 256 + wv * 64 + lane;
      int row = idx >> 3, c = idx & 7;
      gload_lds16((const void*)(Vg + (size_t)row * 512 + kv0 + (c ^ (row & 7)) * 8),
                  (void*)&Vl[buf][(it * 256 + wv * 64) * 8]);
    }
  };

  stageQ();
  stageKV(0, 0);
  __syncthreads();

  bf16x8 aq[2];
#pragma unroll
  for (int kk = 0; kk < 2; ++kk) {
    int row = wv * 16 + l15;
    aq[kk] = *reinterpret_cast<const bf16x8*>(
        &Ql[row * 64 + (((kk * 4 + l4) ^ (row & 7)) * 8)]);
  }

  f32x4 accO[4];
  float mrun[4], lrun[4];
#pragma unroll
  for (int j = 0; j < 4; ++j) accO[j] = f32x4{0.f, 0.f, 0.f, 0.f};
#pragma unroll
  for (int r = 0; r < 4; ++r) { mrun[r] = -3e38f; lrun[r] = 0.f; }

  int cur = 0;
  for (int t = 0; t < 8; ++t) {
    if (t + 1 < 8) stageKV(cur ^ 1, (t + 1) * 64);
    const int kv0 = t * 64;

    f32x4 s[4];
#pragma unroll
    for (int j = 0; j < 4; ++j) s[j] = f32x4{0.f, 0.f, 0.f, 0.f};
#pragma unroll
    for (int kk = 0; kk < 2; ++kk) {
#pragma unroll
      for (int j = 0; j < 4; ++j) {
        int row = j * 16 + l15;
        bf16x8 bk = *reinterpret_cast<const bf16x8*>(
            &Kl[cur][row * 64 + (((kk * 4 + l4) ^ (row & 7)) * 8)]);
        s[j] = __builtin_amdgcn_mfma_f32_16x16x32_bf16(aq[kk], bk, s[j], 0, 0, 0);
      }
    }

#pragma unroll
    for (int j = 0; j < 4; ++j) {
      float mval = mk[kv0 + j * 16 + l15];
#pragma unroll
      for (int r = 0; r < 4; ++r)
        s[j][r] = (mval == 0.f) ? -1e30f : s[j][r];
    }

    float alpha[4];
#pragma unroll
    for (int r = 0; r < 4; ++r) {
      float v = fmaxf(fmaxf(s[0][r], s[1][r]), fmaxf(s[2][r], s[3][r]));
      v = fmaxf(v, __shfl_xor(v, 1));
      v = fmaxf(v, __shfl_xor(v, 2));
      v = fmaxf(v, __shfl_xor(v, 4));
      v = fmaxf(v, __shfl_xor(v, 8));
      float mn = fmaxf(mrun[r], v);
      alpha[r] = __expf(mrun[r] - mn);
      mrun[r] = mn;
    }
    float rs[4] = {0.f, 0.f, 0.f, 0.f};
#pragma unroll
    for (int j = 0; j < 4; ++j)
#pragma unroll
      for (int r = 0; r < 4; ++r) {
        float p = __expf(s[j][r] - mrun[r]);
        s[j][r] = p;
        rs[r] += p;
      }
#pragma unroll
    for (int r = 0; r < 4; ++r) {
      float v = rs[r];
      v += __shfl_xor(v, 1); v += __shfl_xor(v, 2);
      v += __shfl_xor(v, 4); v += __shfl_xor(v, 8);
      lrun[r] = lrun[r] * alpha[r] + v;
#pragma unroll
      for (int j = 0; j < 4; ++j) accO[j][r] *= alpha[r];
    }

#pragma unroll
    for (int j = 0; j < 4; ++j)
#pragma unroll
      for (int r = 0; r < 4; ++r) {
        int qrow = l4 * 4 + r, key = j * 16 + l15;
        __hip_bfloat16 hb = __float2bfloat16(s[j][r]);
        Pl[wv][qrow * 64 + (((key >> 3) ^ (qrow & 7)) * 8) + (key & 7)] =
            *reinterpret_cast<unsigned short*>(&hb);
      }

#pragma unroll
    for (int kc = 0; kc < 2; ++kc) {
      bf16x8 ap = *reinterpret_cast<const bf16x8*>(
          &Pl[wv][l15 * 64 + (((kc * 4 + l4) ^ (l15 & 7)) * 8)]);
#pragma unroll
      for (int j = 0; j < 4; ++j) {
        int row = j * 16 + l15;
        bf16x8 bv2 = *reinterpret_cast<const bf16x8*>(
            &Vl[cur][row * 64 + (((kc * 4 + l4) ^ (row & 7)) * 8)]);
        accO[j] = __builtin_amdgcn_mfma_f32_16x16x32_bf16(ap, bv2, accO[j], 0, 0, 0);
      }
    }
    __syncthreads();
    cur ^= 1;
  }

#pragma unroll
  for (int r = 0; r < 4; ++r) {
    float inv = lrun[r] > 0.f ? 1.f / lrun[r] : 0.f;
#pragma unroll
    for (int j = 0; j < 4; ++j) {
      int row = q0 + wv * 16 + l4 * 4 + r;
      int col = h * 64 + j * 16 + l15;
      ctx[(size_t)(b * 512 + row) * 512 + col] = __float2bfloat16(accO[j][r] * inv);
    }
  }
}

// ---------------------------------------------------------------------------
// ALL weight transposes + bias pack in ONE launch. 23400 blocks x 256 thr.
// ---------------------------------------------------------------------------
__global__ __launch_bounds__(256)
void k_trans_all(const float* __restrict__ Wa1, const float* __restrict__ Wa2,
                 const float* __restrict__ Wf, const float* __restrict__ Wq,
                 const float* __restrict__ Wk, const float* __restrict__ Wv,
                 const float* __restrict__ Wo, const float* __restrict__ Wff1,
                 const float* __restrict__ Wff2, const float* __restrict__ Wg,
                 const float* __restrict__ Wout,
                 const float* __restrict__ bq, const float* __restrict__ bk,
                 const float* __restrict__ bv,
                 __hip_bfloat16* Wa1T, __hip_bfloat16* Wa2T, __hip_bfloat16* WfT,
                 __hip_bfloat16* WqkvT, __hip_bfloat16* WoT, __hip_bfloat16* Wff1T,
                 __hip_bfloat16* Wff2T, __hip_bfloat16* WgT, __hip_bfloat16* WoutT,
                 float* bqkv)
{
  __shared__ float tile[32][33];
  const int bid = blockIdx.x, tid = threadIdx.x;
  const int tx = tid & 31, ty = tid >> 5;

  auto tr = [&](const float* ip, __hip_bfloat16* op, int K, int N, int NTX,
                int t, float scale) {
    int bx = t % NTX, by = t / NTX;
    int n0 = bx * 32, k0 = by * 32;
#pragma unroll
    for (int r = 0; r < 4; ++r) {
      int k = k0 + ty + r * 8, n = n0 + tx;
      if (k < K && n < N) tile[ty + r * 8][tx] = ip[(size_t)k * N + n];
    }
    __syncthreads();
#pragma unroll
    for (int r = 0; r < 4; ++r) {
      int n = n0 + ty + r * 8, k = k0 + tx;
      if (n < N && k < K) op[(size_t)n * K + k] = __float2bfloat16(tile[tx][ty + r * 8] * scale);
    }
  };

  constexpr int DD = 512 * 512, FD = 512 * 2048;
  if (bid < 64)        tr(Wa1, Wa1T, 128, 512, 16, bid, 1.f);
  else if (bid < 320)  tr(Wa2, Wa2T, 512, 512, 16, bid - 64, 1.f);
  else if (bid < 832)  tr(Wf, WfT, 1024, 512, 16, bid - 320, 1.f);
  else if (bid < 1856) { int rl = bid - 832,  z = rl >> 8;
    tr(Wq + (size_t)z * DD, WqkvT + (size_t)z * 3 * DD, 512, 512, 16, rl & 255, 0.125f); }
  else if (bid < 2880) { int rl = bid - 1856, z = rl >> 8;
    tr(Wk + (size_t)z * DD, WqkvT + (size_t)z * 3 * DD + DD, 512, 512, 16, rl & 255, 1.f); }
  else if (bid < 3904) { int rl = bid - 2880, z = rl >> 8;
    tr(Wv + (size_t)z * DD, WqkvT + (size_t)z * 3 * DD + 2 * DD, 512, 512, 16, rl & 255, 1.f); }
  else if (bid < 4928) { int rl = bid - 3904, z = rl >> 8;
    tr(Wo + (size_t)z * DD, WoT + (size_t)z * DD, 512, 512, 16, rl & 255, 1.f); }
  else if (bid < 9024) { int rl = bid - 4928, z = rl >> 10;
    tr(Wff1 + (size_t)z * FD, Wff1T + (size_t)z * FD, 512, 2048, 64, rl & 1023, 1.f); }
  else if (bid < 13120) { int rl = bid - 9024, z = rl >> 10;
    tr(Wff2 + (size_t)z * FD, Wff2T + (size_t)z * FD, 2048, 512, 16, rl & 1023, 1.f); }
  else if (bid < 13376) tr(Wg, WgT, 512, 512, 16, bid - 13120, 1.f);
  else if (bid < 23376) tr(Wout, WoutT, 512, 20000, 625, bid - 13376, 1.f);
  else {
    int i = (bid - 23376) * 256 + tid;           // L*3*512 = 6144 elems
    int d = i & 511, t2 = (i >> 9) % 3, l = i / (3 * 512);
    const float* src = (t2 == 0) ? bq : (t2 == 1) ? bk : bv;
    bqkv[i] = src[l * 512 + d] * (t2 == 0 ? 0.125f : 1.f);
  }
}

// fused: item embedding gather (padding_idx=0) -> cat[:,0:512]; audio cvt -> ab
__global__ void k_front(const int* __restrict__ ids, const float* __restrict__ tbl,
                        const float* __restrict__ audio,
                        __hip_bfloat16* __restrict__ cat, __hip_bfloat16* __restrict__ ab) {
  int n = blockIdx.x, t = threadIdx.x;
  int id = ids[n];
  const float* src = tbl + (size_t)id * 512;
  size_t dst = (size_t)n * 1024;
  float a0 = (id == 0) ? 0.f : src[t];
  float a1 = (id == 0) ? 0.f : src[t + 256];
  cat[dst + t] = __float2bfloat16(a0);
  cat[dst + t + 256] = __float2bfloat16(a1);
  if (t < 128) ab[(size_t)n * 128 + t] = __float2bfloat16(audio[(size_t)n * 128 + t]);
}

__global__ void k_ln(const float* __restrict__ x, const float* __restrict__ y,
                     const float* __restrict__ gam, const float* __restrict__ bet,
                     float* __restrict__ xout, __hip_bfloat16* __restrict__ xb) {
  int row = blockIdx.x, t = threadIdx.x;
  size_t base = (size_t)row * 512;
  float v0 = x[base + t], v1 = x[base + t + 256];
  if (y) { v0 += y[base + t]; v1 += y[base + t + 256]; }
  __shared__ float sm[4];
  float s = v0 + v1;
  for (int o = 32; o; o >>= 1) s += __shfl_xor(s, o);
  if ((t & 63) == 0) sm[t >> 6] = s;
  __syncthreads();
  float mean = (sm[0] + sm[1] + sm[2] + sm[3]) * (1.f / 512.f);
  __syncthreads();
  float d0 = v0 - mean, d1 = v1 - mean;
  float qq = d0 * d0 + d1 * d1;
  for (int o = 32; o; o >>= 1) qq += __shfl_xor(qq, o);
  if ((t & 63) == 0) sm[t >> 6] = qq;
  __syncthreads();
  float var = (sm[0] + sm[1] + sm[2] + sm[3]) * (1.f / 512.f);
  float rs = rsqrtf(var + 1e-5f);
  float o0 = d0 * rs * gam[t] + bet[t];
  float o1 = d1 * rs * gam[t + 256] + bet[t + 256];
  xout[base + t] = o0;
  xout[base + t + 256] = o1;
  xb[base + t] = __float2bfloat16(o0);
  xb[base + t + 256] = __float2bfloat16(o1);
}

// ---------------------------------------------------------------------------
extern "C" void kernel_launch(void* const* d_in, const int* in_sizes, int n_in,
                              void* d_out, int out_size, void* d_ws, size_t ws_size,
                              hipStream_t stream) {
  typedef __hip_bfloat16 bf;
  const int*   item_ids = (const int*)  d_in[0];
  const float* audio    = (const float*)d_in[1];
  const float* organic  = (const float*)d_in[2];
  const float* mask     = (const float*)d_in[3];
  const float* emb      = (const float*)d_in[4];
  const float* pe       = (const float*)d_in[5];
  const float* Wa1 = (const float*)d_in[6],  *ba1 = (const float*)d_in[7];
  const float* Wa2 = (const float*)d_in[8],  *ba2 = (const float*)d_in[9];
  const float* Wf  = (const float*)d_in[10], *bfb = (const float*)d_in[11];
  const float* Wq  = (const float*)d_in[12], *bq  = (const float*)d_in[13];
  const float* Wk  = (const float*)d_in[14], *bk  = (const float*)d_in[15];
  const float* Wv  = (const float*)d_in[16], *bv  = (const float*)d_in[17];
  const float* Wo  = (const float*)d_in[18], *bo  = (const float*)d_in[19];
  const float* ln1s = (const float*)d_in[22], *ln1b = (const float*)d_in[23];
  const float* ln2s = (const float*)d_in[24], *ln2b = (const float*)d_in[25];
  const float* Wff1 = (const float*)d_in[26], *bff1 = (const float*)d_in[27];
  const float* Wff2 = (const float*)d_in[28], *bff2 = (const float*)d_in[29];
  const float* lnOs = (const float*)d_in[30], *lnOb = (const float*)d_in[31];
  const float* Wg   = (const float*)d_in[32], *bg   = (const float*)d_in[33];
  const float* Wout = (const float*)d_in[34], *bout = (const float*)d_in[35];
  float* out = (float*)d_out;

  char* ws = (char*)d_ws;
  size_t off = 0;
  auto alloc = [&](size_t bytes) -> char* {
    char* p = ws + off;
    off = (off + bytes + 255) & ~(size_t)255;
    return p;
  };
  bf* Wa1T = (bf*)alloc((size_t)512 * 128 * 2);
  bf* Wa2T = (bf*)alloc((size_t)512 * 512 * 2);
  bf* WfT  = (bf*)alloc((size_t)512 * 1024 * 2);
  bf* WqkvT = (bf*)alloc((size_t)L_ * 3 * D_ * D_ * 2);   // [L][3*D][D]
  bf* WoT  = (bf*)alloc((size_t)L_ * D_ * D_ * 2);
  bf* Wff1T = (bf*)alloc((size_t)L_ * DFF_ * D_ * 2);
  bf* Wff2T = (bf*)alloc((size_t)L_ * D_ * DFF_ * 2);
  bf* WgT   = (bf*)alloc((size_t)512 * 512 * 2);
  bf* WoutT = (bf*)alloc((size_t)NOUT_PAD * 512 * 2);     // pad rows hold finite poison
  float* bqkv = (float*)alloc((size_t)L_ * 3 * 512 * 4);
  bf* ab    = (bf*)alloc((size_t)N_ * AD_ * 2);
  bf* cat   = (bf*)alloc((size_t)N_ * 1024 * 2);
  bf* ah    = (bf*)alloc((size_t)N_ * 512 * 2);
  float* xf = (float*)alloc((size_t)N_ * 512 * 4);
  bf* xb    = (bf*)alloc((size_t)N_ * 512 * 2);
  bf* qkv   = (bf*)alloc((size_t)3 * N_ * 512 * 2);       // [3][N][D] (v slot unused)
  bf* vt    = (bf*)alloc((size_t)B_ * H_ * DK_ * S_ * 2);
  bf* ctxb  = (bf*)alloc((size_t)N_ * 512 * 2);
  float* ybuf = (float*)alloc((size_t)N_ * 512 * 4);
  bf* ff1b  = (bf*)alloc((size_t)N_ * DFF_ * 2);
  bf* xg    = (bf*)alloc((size_t)N_ * 512 * 2);
  if (off > ws_size) return;  // loud failure (output stays poisoned)

  bf* qb = qkv;
  bf* kb = qkv + (size_t)N_ * 512;

  // ALL weight transposes + bias pack in one launch
  k_trans_all<<<23400, 256, 0, stream>>>(Wa1, Wa2, Wf, Wq, Wk, Wv, Wo, Wff1, Wff2,
      Wg, Wout, bq, bk, bv,
      Wa1T, Wa2T, WfT, WqkvT, WoT, Wff1T, Wff2T, WgT, WoutT, bqkv);

  // front-end
  k_front<<<N_, 256, 0, stream>>>(item_ids, emb, audio, cat, ab);
  gemm2<128, 64, 1, 1><<<dim3(32, 8), 256, 0, stream>>>(ab, 128, Wa1T, 128,
      (void*)ah, 512, ba1, nullptr, nullptr, nullptr, 128, 512);
  gemm2<64, 64, 1, 0><<<dim3(64, 8), 256, 0, stream>>>(ah, 512, Wa2T, 512,
      (void*)(cat + 512), 1024, ba2, nullptr, nullptr, nullptr, 512, 512);
  gemm2<64, 64, 2, 1><<<dim3(64, 8), 256, 0, stream>>>(cat, 1024, WfT, 1024,
      (void*)xf, 512, bfb, (void*)xb, (const void*)pe, nullptr, 1024, 512);

  // layers
  for (int l = 0; l < L_; ++l) {
    // wide QKV, BN=64 (grid 32x24 = 768 blocks, 3 blocks/CU)
    gemm2<128, 64, 3, 0><<<dim3(32, 24), 256, 0, stream>>>(xb, 512,
        WqkvT + (size_t)l * 3 * D_ * D_, 512, (void*)qkv, 512,
        bqkv + (size_t)l * 3 * 512, (void*)vt, nullptr, nullptr, 512, 1536);
    k_flash<<<dim3(8, B_ * H_), 256, 0, stream>>>(qb, kb, vt, mask, ctxb);
    // Wo + fused residual (xf) -> ybuf : BM=64 for 2x block parallelism
    gemm2<64, 64, 5, 0><<<dim3(64, 8), 256, 0, stream>>>(ctxb, 512,
        WoT + (size_t)l * D_ * D_, 512, (void*)ybuf, 512, bo + l * D_,
        nullptr, (const void*)xf, nullptr, 512, 512);
    k_ln<<<N_, 256, 0, stream>>>(ybuf, nullptr, ln1s + l * D_, ln1b + l * D_, xf, xb);
    // FF1: 64x128 tile (grid 64x16 = 1024 blocks, 48 KB LDS, 3 blocks/CU)
    gemm2<64, 128, 1, 1><<<dim3(64, 16), 256, 0, stream>>>(xb, 512,
        Wff1T + (size_t)l * DFF_ * D_, 512, (void*)ff1b, 2048, bff1 + l * DFF_,
        nullptr, nullptr, nullptr, 512, 2048);
    // FF2 + fused residual (xf) -> ybuf : BM=64
    gemm2<64, 64, 5, 0><<<dim3(64, 8), 256, 0, stream>>>(ff1b, 2048,
        Wff2T + (size_t)l * D_ * DFF_, 2048, (void*)ybuf, 512, bff2 + l * D_,
        nullptr, (const void*)xf, nullptr, 2048, 512);
    k_ln<<<N_, 256, 0, stream>>>(ybuf, nullptr, ln2s + l * D_, ln2b + l * D_, xf, xb);
  }

  // final LN + gate(fused) + logits
  k_ln<<<N_, 256, 0, stream>>>(xf, nullptr, lnOs, lnOb, xf, xb);
  gemm2<64, 64, 4, 0><<<dim3(64, 8), 256, 0, stream>>>(xb, 512, WgT, 512,
      (void*)xg, 512, bg, (const void*)xf, (const void*)organic,
      (const void*)(Wg + (size_t)512 * 512), 512, 512);
  // logits: 4096x20000x512 -> 256x256 BK=32 2-phase, LDS-bounce NT epilogue
  gemm_big<<<dim3(16, 79), 512, 0, stream>>>(xg, 512, WoutT, 512,
      out, 20000, bout, 512, 20000);
}